// Round 2
// baseline (634.858 us; speedup 1.0000x reference)
//
#include <hip/hip_runtime.h>

typedef unsigned short u16;
typedef __attribute__((ext_vector_type(8))) short short8;   // 8 x bf16 (4 VGPRs) MFMA A/B frag
typedef __attribute__((ext_vector_type(4))) float f32x4;    // MFMA C/D frag

__device__ __forceinline__ u16 f2b(float f) {               // f32 -> bf16 RNE
    union { float f; unsigned u; } v; v.f = f;
    unsigned u = v.u;
    u += 0x7fffu + ((u >> 16) & 1u);
    return (u16)(u >> 16);
}
__device__ __forceinline__ float b2f(u16 s) {
    union { unsigned u; float f; } v; v.u = ((unsigned)s) << 16;
    return v.f;
}

// Sizes: B=2, N=1024, T=2048 tokens, H=8, D=256, DK=128, NK=256 keys, TOPK=16, NUM_KV=65536.

// ---------------- K0: casts + transposes (all jobs are 524288 elems) ----------------
__global__ __launch_bounds__(256) void prep_kernel(
    const float* __restrict__ x, const float* __restrict__ wq,
    const float* __restrict__ wo, const float* __restrict__ pkk,
    u16* __restrict__ xb, u16* __restrict__ wq_t, u16* __restrict__ wo_t,
    float* __restrict__ pkt)
{
    int job = blockIdx.y;
    for (int i = blockIdx.x * 256 + threadIdx.x; i < 524288; i += 256 * 256) {
        if (job == 0)      xb[i] = f2b(x[i]);
        else if (job == 1) { int n = i >> 8,  k = i & 255;  wq_t[i] = f2b(wq[k * 2048 + n]); }  // [2048][256] = Wq^T
        else if (job == 2) { int n = i >> 11, k = i & 2047; wo_t[i] = f2b(wo[k * 256 + n]); }   // [256][2048] = Wo^T
        else {
            // pkt[p][h][d][key] = pk_keys[p][key][h][d]   (f32, for sims GEMM B operand)
            int key = i & 255, d = (i >> 8) & 127, h = (i >> 15) & 7, p = i >> 18;
            pkt[i] = pkk[(((p << 8) + key) * 8 + h) * 128 + d];
        }
    }
}

// ---------------- f32 VALU GEMM: C = A @ B (row-major A [M][K], B [K][N]) ----------------
// 64x64 tile, 256 threads, 16x16 thread grid, 4x4 outputs/thread, BK=16. Exact f32 for retrieval.
__global__ __launch_bounds__(256) void gemm_f32(
    const float* __restrict__ A, int aZp, int aZh, int lda,
    const float* __restrict__ B, int bZp, int bZh, int ldb,
    float* __restrict__ C, int cZp, int cZh, int ldc, int K)
{
    int z = blockIdx.z, zp = z >> 3, zh = z & 7;
    A += (size_t)zp * aZp + (size_t)zh * aZh;
    B += (size_t)zp * bZp + (size_t)zh * bZh;
    size_t cb = (size_t)zp * cZp + (size_t)zh * cZh;
    int m0 = blockIdx.x * 64, n0 = blockIdx.y * 64;
    int tid = threadIdx.x, tx = tid & 15, ty = tid >> 4;
    __shared__ float As[16][68];   // [k][m], pad 68 keeps float4 reads 16B-aligned
    __shared__ float Bs[16][64];   // [k][n]
    int ar = tid >> 2, ac4 = (tid & 3) * 4;     // A stage: row, k-quad
    int br = tid >> 4, bc4 = (tid & 15) * 4;    // B stage: k-row, n-quad
    float acc[4][4] = {};
    for (int k0 = 0; k0 < K; k0 += 16) {
        __syncthreads();
        float4 av = *(const float4*)(A + (size_t)(m0 + ar) * lda + k0 + ac4);
        As[ac4 + 0][ar] = av.x; As[ac4 + 1][ar] = av.y;
        As[ac4 + 2][ar] = av.z; As[ac4 + 3][ar] = av.w;
        *(float4*)&Bs[br][bc4] = *(const float4*)(B + (size_t)(k0 + br) * ldb + n0 + bc4);
        __syncthreads();
        #pragma unroll
        for (int k = 0; k < 16; k++) {
            float4 a4 = *(const float4*)&As[k][ty * 4];
            float4 b4 = *(const float4*)&Bs[k][tx * 4];
            float aa[4] = {a4.x, a4.y, a4.z, a4.w};
            float bb[4] = {b4.x, b4.y, b4.z, b4.w};
            #pragma unroll
            for (int i = 0; i < 4; i++)
                #pragma unroll
                for (int j = 0; j < 4; j++) acc[i][j] += aa[i] * bb[j];
        }
    }
    #pragma unroll
    for (int i = 0; i < 4; i++)
        #pragma unroll
        for (int j = 0; j < 4; j++)
            C[cb + (size_t)(m0 + ty * 4 + i) * ldc + n0 + tx * 4 + j] = acc[i][j];
}

// ---------------- bf16 MFMA GEMM: C[m][n] = alpha * sum_k A[m][k] * BT[n][k] ----------------
template<int OUT_BF16>
__global__ __launch_bounds__(256) void gemm_bt(
    const u16* __restrict__ A, int lda,
    const u16* __restrict__ BT, int ldb,
    void* __restrict__ Cv, int ldc,
    int K, float alpha)
{
    int m0 = blockIdx.x * 64, n0 = blockIdx.y * 64;
    int tid = threadIdx.x, lane = tid & 63, wid = tid >> 6;
    int wr = wid >> 1, wc = wid & 1, l15 = lane & 15, cg = lane >> 4;
    __shared__ __align__(16) u16 as_[64][40];  // rows 80B (16B-aligned), pad breaks conflicts
    __shared__ __align__(16) u16 bs_[64][40];
    f32x4 acc[2][2];
    #pragma unroll
    for (int m = 0; m < 2; m++)
        #pragma unroll
        for (int n = 0; n < 2; n++) acc[m][n] = (f32x4){0.f, 0.f, 0.f, 0.f};
    int rs = tid >> 2, qs = tid & 3;
    for (int k0 = 0; k0 < K; k0 += 32) {
        __syncthreads();
        *(uint4*)&as_[rs][qs * 8] = *(const uint4*)(A  + (size_t)(m0 + rs) * lda + k0 + qs * 8);
        *(uint4*)&bs_[rs][qs * 8] = *(const uint4*)(BT + (size_t)(n0 + rs) * ldb + k0 + qs * 8);
        __syncthreads();
        short8 af[2], bf[2];
        #pragma unroll
        for (int m = 0; m < 2; m++) af[m] = *(const short8*)&as_[wr * 32 + m * 16 + l15][cg * 8];
        #pragma unroll
        for (int n = 0; n < 2; n++) bf[n] = *(const short8*)&bs_[wc * 32 + n * 16 + l15][cg * 8];
        #pragma unroll
        for (int m = 0; m < 2; m++)
            #pragma unroll
            for (int n = 0; n < 2; n++)
                acc[m][n] = __builtin_amdgcn_mfma_f32_16x16x32_bf16(af[m], bf[n], acc[m][n], 0, 0, 0);
    }
    #pragma unroll
    for (int m = 0; m < 2; m++)
        #pragma unroll
        for (int n = 0; n < 2; n++)
            #pragma unroll
            for (int r = 0; r < 4; r++) {
                int row = m0 + wr * 32 + m * 16 + cg * 4 + r;   // C/D: row = cg*4+reg
                int col = n0 + wc * 32 + n * 16 + l15;          //      col = lane&15
                float v = acc[m][n][r] * alpha;
                if (OUT_BF16) ((u16*)Cv)[(size_t)row * ldc + col] = f2b(v);
                else          ((float*)Cv)[(size_t)row * ldc + col] = v;
            }
}

// ---------------- K3: fused two-stage top-16 + softmax. 1 wave per (t,h). ----------------
// Tie-break = lowest flat index (matches jax.lax.top_k stable descending sort).
__global__ __launch_bounds__(256) void topk_kernel(
    const float* __restrict__ sims, float* __restrict__ fw, int* __restrict__ fidx)
{
    int wid = threadIdx.x >> 6, lane = threadIdx.x & 63;
    int u = blockIdx.x * 4 + wid;     // u = t*8 + h
    int t = u >> 3, h = u & 7;
    __shared__ float lv[4][2][16];
    __shared__ int   li[4][2][16];
    // stage 1: per-p top-16 of 256
    #pragma unroll
    for (int p = 0; p < 2; p++) {
        const float* sp = sims + ((size_t)(p * 2048 + t) * 8 + h) * 256;
        float s[4];
        #pragma unroll
        for (int j = 0; j < 4; j++) s[j] = sp[j * 64 + lane];
        for (int it = 0; it < 16; ++it) {
            float bv = s[0]; int bi = lane;
            #pragma unroll
            for (int j = 1; j < 4; j++) { if (s[j] > bv) { bv = s[j]; bi = j * 64 + lane; } }
            for (int off = 1; off < 64; off <<= 1) {
                float ov = __shfl_xor(bv, off, 64); int oi = __shfl_xor(bi, off, 64);
                if (ov > bv || (ov == bv && oi < bi)) { bv = ov; bi = oi; }
            }
            if (lane == 0) { lv[wid][p][it] = bv; li[wid][p][it] = bi; }
            if ((bi & 63) == lane) s[bi >> 6] = -1e30f;
        }
    }
    __syncthreads();
    // stage 2: 16x16 cartesian sums, top-16, softmax. candidate c = i*16+j (i outer p0, j inner p1)
    float c[4];
    #pragma unroll
    for (int j = 0; j < 4; j++) { int cc = j * 64 + lane; c[j] = lv[wid][0][cc >> 4] + lv[wid][1][cc & 15]; }
    float myv = 0.f; int myc = 0;
    for (int it = 0; it < 16; ++it) {
        float bv = c[0]; int bi = lane;
        #pragma unroll
        for (int j = 1; j < 4; j++) { if (c[j] > bv) { bv = c[j]; bi = j * 64 + lane; } }
        for (int off = 1; off < 64; off <<= 1) {
            float ov = __shfl_xor(bv, off, 64); int oi = __shfl_xor(bi, off, 64);
            if (ov > bv || (ov == bv && oi < bi)) { bv = ov; bi = oi; }
        }
        if ((lane & 15) == it) { myv = bv; myc = bi; }
        if ((bi & 63) == lane) c[bi >> 6] = -1e30f;
    }
    float v0 = __shfl(myv, 0, 16);           // max = first selected (descending)
    float e = __expf(myv - v0);
    float ssum = e;
    for (int off = 1; off < 16; off <<= 1) ssum += __shfl_xor(ssum, off, 16);
    if (lane < 16) {
        int gi = li[wid][0][myc >> 4] + (li[wid][1][myc & 15] << 8) + (h << 16);  // idx0 + 256*idx1 + h*NUM_KV
        fw[u * 16 + lane]   = e / ssum;
        fidx[u * 16 + lane] = gi;
    }
}

// ---------------- K4: weighted gather from keys/values tables -> bf16 k,v ----------------
__global__ __launch_bounds__(256) void gather_kernel(
    const float* __restrict__ ktab, const float* __restrict__ vtab,
    const float* __restrict__ fw, const int* __restrict__ fidx,
    u16* __restrict__ kg, u16* __restrict__ vg)
{
    int u = blockIdx.x;              // t*8 + h
    int t = u >> 3, h = u & 7, d = threadIdx.x;
    int b = t >> 10, n = t & 1023;
    float aK = 0.f, aV = 0.f;
    #pragma unroll
    for (int r = 0; r < 16; r++) {
        float w = fw[u * 16 + r];
        size_t row = (size_t)fidx[u * 16 + r];
        aK += w * ktab[row * 256 + d];
        aV += w * vtab[row * 256 + d];
    }
    size_t o = ((size_t)(b * 8 + h) * 1024 + n) * 256 + d;   // [bh][n][d]
    kg[o] = f2b(aK);
    vg[o] = f2b(aV);
}

// ---------------- K5: transpose v [bh][n][d] -> [bh][d][n] (for PV B-fragments) ----------------
__global__ __launch_bounds__(256) void vtrans_kernel(const u16* __restrict__ vg, u16* __restrict__ vtg)
{
    int u = blockIdx.x;                  // 16 bh * 4 dtiles * 16 ntiles
    int bh = u >> 6, dt4 = (u >> 4) & 3, nt = u & 15;
    __shared__ float tile[64][65];
    int tid = threadIdx.x;
    #pragma unroll
    for (int p = 0; p < 16; p++) {
        int flat = p * 256 + tid; int rr = flat >> 6, cc = flat & 63;
        tile[rr][cc] = b2f(vg[((size_t)bh * 1024 + nt * 64 + rr) * 256 + dt4 * 64 + cc]);
    }
    __syncthreads();
    #pragma unroll
    for (int p = 0; p < 16; p++) {
        int flat = p * 256 + tid; int od = flat >> 6, on = flat & 63;
        vtg[((size_t)bh * 256 + dt4 * 64 + od) * 1024 + nt * 64 + on] = f2b(tile[on][od]);
    }
}

// ---------------- K6: causal flash attention, 1 wave / block, i-tile=16, kv-chunk=32 ----------------
__global__ __launch_bounds__(64) void attn_kernel(
    const u16* __restrict__ qb, const u16* __restrict__ kg, const u16* __restrict__ vtg,
    u16* __restrict__ attb)
{
    int bid = blockIdx.x;
    int bh = bid >> 6, it = bid & 63;
    int b = bh >> 3, h = bh & 7;
    int i0 = it * 16;
    int lane = threadIdx.x, l15 = lane & 15, cg = lane >> 4;

    __shared__ __align__(16) char ksm[32 * 512];      // K chunk [32][256] bf16, XOR-swizzled 16B groups
    __shared__ __align__(16) u16  vts[256 * 40];      // V^T chunk [256][32] bf16, pad-40 rows
    __shared__ __align__(16) u16  pls[16 * 40];       // P tile [16][32] bf16, pad-40 rows

    // Q A-fragments in registers: qf[kc], k = kc*32 + cg*8 + j
    short8 qf[8];
    const u16* qrow = qb + (size_t)(b * 1024 + i0 + l15) * 2048 + h * 256 + cg * 8;
    #pragma unroll
    for (int kc = 0; kc < 8; kc++) qf[kc] = *(const short8*)(qrow + kc * 32);

    f32x4 of[16];
    #pragma unroll
    for (int dt = 0; dt < 16; dt++) of[dt] = (f32x4){0.f, 0.f, 0.f, 0.f};
    float m[4] = {-1e30f, -1e30f, -1e30f, -1e30f};
    float l[4] = {0.f, 0.f, 0.f, 0.f};

    int nch = (it >> 1) + 1;
    const u16* kbase = kg  + (size_t)bh * 1024 * 256;
    const u16* vbase = vtg + (size_t)bh * 256 * 1024;

    for (int jc = 0; jc < nch; ++jc) {
        int j0 = jc * 32;
        __syncthreads();
        // stage K: 32 rows x 32 groups of 16B, swizzle: group g -> g ^ (row&7)
        #pragma unroll
        for (int u = 0; u < 16; ++u) {
            int flat = u * 64 + lane; int r = flat >> 5, g = flat & 31;
            uint4 val = *(const uint4*)(kbase + (size_t)(j0 + r) * 256 + g * 8);
            *(uint4*)(ksm + r * 512 + ((g ^ (r & 7)) << 4)) = val;
        }
        // stage V^T: 256 rows(d) x 4 groups of 16B, pad-40 rows
        #pragma unroll
        for (int u = 0; u < 16; ++u) {
            int flat = u * 64 + lane; int d = flat >> 2, g = flat & 3;
            uint4 val = *(const uint4*)(vbase + (size_t)d * 1024 + j0 + g * 8);
            *(uint4*)((char*)vts + d * 80 + g * 16) = val;
        }
        __syncthreads();

        // QK^T: S[16 rows i][32 cols j] as two 16x16 C tiles
        f32x4 c0 = (f32x4){0.f, 0.f, 0.f, 0.f};
        f32x4 c1 = (f32x4){0.f, 0.f, 0.f, 0.f};
        #pragma unroll
        for (int kc = 0; kc < 8; kc++) {
            int g = kc * 4 + cg;
            short8 b0 = *(const short8*)(ksm + l15 * 512        + ((g ^ (l15 & 7)) << 4));
            short8 b1 = *(const short8*)(ksm + (16 + l15) * 512 + ((g ^ ((16 + l15) & 7)) << 4));
            c0 = __builtin_amdgcn_mfma_f32_16x16x32_bf16(qf[kc], b0, c0, 0, 0, 0);
            c1 = __builtin_amdgcn_mfma_f32_16x16x32_bf16(qf[kc], b1, c1, 0, 0, 0);
        }
        // causal mask (only last chunk straddles the diagonal)
        if (jc == nch - 1) {
            #pragma unroll
            for (int r = 0; r < 4; r++) {
                int ig = i0 + cg * 4 + r;
                if (j0 + l15 > ig)      c0[r] = -1e30f;
                if (j0 + 16 + l15 > ig) c1[r] = -1e30f;
            }
        }
        // online softmax; row r lives at lanes sharing cg, reg r
        float es[4];
        #pragma unroll
        for (int r = 0; r < 4; r++) {
            float mr = fmaxf(c0[r], c1[r]);
            for (int off = 1; off < 16; off <<= 1) mr = fmaxf(mr, __shfl_xor(mr, off, 16));
            float mn = fmaxf(m[r], mr);
            float p0 = __expf(c0[r] - mn), p1 = __expf(c1[r] - mn);
            c0[r] = p0; c1[r] = p1;
            float rsum = p0 + p1;
            for (int off = 1; off < 16; off <<= 1) rsum += __shfl_xor(rsum, off, 16);
            es[r] = __expf(m[r] - mn);
            l[r] = l[r] * es[r] + rsum;
            m[r] = mn;
        }
        // P -> LDS (bf16), rescale O
        #pragma unroll
        for (int r = 0; r < 4; r++) {
            int row = cg * 4 + r;
            pls[row * 40 + l15]      = f2b(c0[r]);
            pls[row * 40 + 16 + l15] = f2b(c1[r]);
        }
        #pragma unroll
        for (int dt = 0; dt < 16; dt++)
            #pragma unroll
            for (int r = 0; r < 4; r++) of[dt][r] *= es[r];
        __syncthreads();
        // PV: A = P[16][32], B = V[32][16-col d-tile]
        short8 pa = *(const short8*)((char*)pls + l15 * 80 + cg * 16);
        #pragma unroll
        for (int dt = 0; dt < 16; ++dt) {
            short8 bv = *(const short8*)((char*)vts + (dt * 16 + l15) * 80 + cg * 16);
            of[dt] = __builtin_amdgcn_mfma_f32_16x16x32_bf16(pa, bv, of[dt], 0, 0, 0);
        }
    }
    // epilogue: att[t][h*256+d] = O/l  (== out.transpose(0,2,1,3).reshape)
    float rl[4];
    #pragma unroll
    for (int r = 0; r < 4; r++) rl[r] = 1.f / l[r];
    u16* orow = attb + (size_t)(b * 1024 + i0) * 2048 + h * 256;
    #pragma unroll
    for (int dt = 0; dt < 16; dt++)
        #pragma unroll
        for (int r = 0; r < 4; r++)
            orow[(size_t)(cg * 4 + r) * 2048 + dt * 16 + l15] = f2b(of[dt][r] * rl[r]);
}

// ---------------- launcher ----------------
extern "C" void kernel_launch(void* const* d_in, const int* in_sizes, int n_in,
                              void* d_out, int out_size, void* d_ws, size_t ws_size,
                              hipStream_t stream) {
    (void)in_sizes; (void)n_in; (void)out_size; (void)ws_size;
    const float* x    = (const float*)d_in[0];
    const float* wqpk = (const float*)d_in[1];
    const float* pkk  = (const float*)d_in[2];
    const float* wq   = (const float*)d_in[3];
    const float* ktab = (const float*)d_in[4];
    const float* vtab = (const float*)d_in[5];
    const float* wo   = (const float*)d_in[6];
    float* out = (float*)d_out;

    char* w = (char*)d_ws;
    const size_t MB = 1u << 20;
    u16*   xb     = (u16*)(w + 0 * MB);    // [2048][256] bf16
    u16*   wq_t   = (u16*)(w + 1 * MB);    // [2048][256] bf16
    u16*   wo_t   = (u16*)(w + 2 * MB);    // [256][2048] bf16
    float* pkt    = (float*)(w + 3 * MB);  // [2][8][128][256] f32 (2 MB)
    float* qpk_f  = (float*)(w + 5 * MB);  // [2048][2048] f32 (16 MB), dead after sims GEMM
    u16*   q_b    = (u16*)(w + 21 * MB);   // [2048][2048] bf16 (8 MB), pre-scaled by 1/16
    float* sims   = (float*)(w + 29 * MB); // [2][2048][8][256] f32 (32 MB), dead after topk
    float* fw     = (float*)(w + 61 * MB); // [16384][16]
    int*   fidx   = (int*)(w + 62 * MB);   // [16384][16]
    u16*   kg     = (u16*)(w + 29 * MB);   // [16][1024][256] bf16 (8 MB), overlays dead sims
    u16*   vg     = (u16*)(w + 37 * MB);   // [16][1024][256] bf16 (8 MB)
    u16*   vtg    = (u16*)(w + 45 * MB);   // [16][256][1024] bf16 (8 MB)
    u16*   attb   = (u16*)(w + 5 * MB);    // [2048][2048] bf16 (8 MB), overlays dead qpk_f

    prep_kernel<<<dim3(256, 4), 256, 0, stream>>>(x, wq, wo, pkk, xb, wq_t, wo_t, pkt);
    // qpk = x @ Wq_pk   (exact f32, VALU)
    gemm_f32<<<dim3(32, 32, 1), 256, 0, stream>>>(x, 0, 0, 256, wqpk, 0, 0, 2048,
                                                  qpk_f, 0, 0, 2048, 256);
    // sims[p][t][h][k] = qpk[t,(p,h,:)] . pk_keys[p,k,h,:]  (exact f32), z = p*8+h
    gemm_f32<<<dim3(32, 4, 16), 256, 0, stream>>>(qpk_f, 1024, 128, 2048,
                                                  pkt, 262144, 32768, 256,
                                                  sims, 4194304, 256, 2048, 128);
    // q = (x @ Wq) * DIM^-0.5   (bf16 out, MFMA)
    gemm_bt<1><<<dim3(32, 32, 1), 256, 0, stream>>>(xb, 256, wq_t, 256, q_b, 2048, 256, 0.0625f);
    topk_kernel<<<4096, 256, 0, stream>>>(sims, fw, fidx);
    gather_kernel<<<16384, 256, 0, stream>>>(ktab, vtab, fw, fidx, kg, vg);
    vtrans_kernel<<<1024, 256, 0, stream>>>(vg, vtg);
    attn_kernel<<<1024, 64, 0, stream>>>(q_b, kg, vtg, attb);
    // out = att @ Wo   (f32 out, MFMA)
    gemm_bt<0><<<dim3(32, 4, 1), 256, 0, stream>>>(attb, 2048, wo_t, 2048, out, 256, 2048, 1.f);
}

// Round 3
// 552.629 us; speedup vs baseline: 1.1488x; 1.1488x over previous
//
#include <hip/hip_runtime.h>

typedef unsigned short u16;
typedef __attribute__((ext_vector_type(8))) short short8;   // 8 x bf16 (4 VGPRs) MFMA A/B frag
typedef __attribute__((ext_vector_type(4))) float f32x4;    // MFMA C/D frag

__device__ __forceinline__ u16 f2b(float f) {               // f32 -> bf16 RNE
    union { float f; unsigned u; } v; v.f = f;
    unsigned u = v.u;
    u += 0x7fffu + ((u >> 16) & 1u);
    return (u16)(u >> 16);
}
__device__ __forceinline__ float b2f(u16 s) {
    union { unsigned u; float f; } v; v.u = ((unsigned)s) << 16;
    return v.f;
}

// Sizes: B=2, N=1024, T=2048 tokens, H=8, D=256, DK=128, NK=256 keys, TOPK=16, NUM_KV=65536.

// ---------------- K0: elementwise bf16 hi/lo splits (x, pk_keys-permuted) ----------------
__global__ __launch_bounds__(256) void prep_elem(
    const float* __restrict__ x, const float* __restrict__ pkk,
    u16* __restrict__ xhi, u16* __restrict__ xlo,
    u16* __restrict__ pkthi, u16* __restrict__ pktlo)
{
    int job = blockIdx.y;
    for (int i = blockIdx.x * 256 + threadIdx.x; i < 524288; i += 256 * 256) {
        if (job == 0) {
            float v = x[i];
            u16 hi = f2b(v); xhi[i] = hi; xlo[i] = f2b(v - b2f(hi));
        } else {
            // pkt[p][h][key][d] = pk_keys[p][key][h][d]; d innermost both sides -> coalesced
            int d = i & 127, key = (i >> 7) & 255, h = (i >> 15) & 7, p = i >> 18;
            float v = pkk[(((p << 8) + key) * 8 + h) * 128 + d];
            u16 hi = f2b(v); pkthi[i] = hi; pktlo[i] = f2b(v - b2f(hi));
        }
    }
}

// ---------------- K1: tiled 64x64 transposes, coalesced both sides ----------------
// job0: Wq_pk [256][2048] -> [2048][256] hi/lo; job1: Wq same -> bf16; job2: Wo [2048][256] -> [256][2048] bf16
__global__ __launch_bounds__(256) void trans_kernel(
    const float* __restrict__ wqpk, const float* __restrict__ wq, const float* __restrict__ wo,
    u16* __restrict__ wqpk_thi, u16* __restrict__ wqpk_tlo,
    u16* __restrict__ wq_t, u16* __restrict__ wo_t)
{
    int job = blockIdx.y, tile = blockIdx.x, tid = threadIdx.x;
    const float* in = (job == 0) ? wqpk : (job == 1) ? wq : wo;
    int R = (job == 2) ? 2048 : 256;
    int C = (job == 2) ? 256 : 2048;
    int CT = C >> 6;
    int tr = tile / CT, tc = tile % CT;
    __shared__ float t[64][65];
    #pragma unroll
    for (int p = 0; p < 16; p++) {
        int row = p * 4 + (tid >> 6), col = tid & 63;
        t[row][col] = in[(size_t)(tr * 64 + row) * C + tc * 64 + col];
    }
    __syncthreads();
    #pragma unroll
    for (int p = 0; p < 16; p++) {
        int row = p * 4 + (tid >> 6), col = tid & 63;
        float v = t[col][row];
        size_t o = (size_t)(tc * 64 + row) * R + tr * 64 + col;
        if (job == 0) { u16 hi = f2b(v); wqpk_thi[o] = hi; wqpk_tlo[o] = f2b(v - b2f(hi)); }
        else if (job == 1) wq_t[o] = f2b(v);
        else               wo_t[o] = f2b(v);
    }
}

// ---------------- bf16x3 MFMA GEMM (near-f32 exact): C = (Ahi+Alo)(Bhi+Blo)^T, drop lo*lo ----------------
// 64x64 tile, 4 waves, 16x16x32 MFMA, BK=32. OUT_SPLIT: write hi/lo bf16 pair; else f32.
template<int OUT_SPLIT>
__global__ __launch_bounds__(256) void gemm_x3(
    const u16* __restrict__ ahi, const u16* __restrict__ alo, int aZp, int aZh, int lda,
    const u16* __restrict__ bhi, const u16* __restrict__ blo, int bZp, int bZh, int ldb,
    void* __restrict__ c0v, void* __restrict__ c1v, int cZp, int cZh, int ldc, int K)
{
    int z = blockIdx.z, zp = z >> 3, zh = z & 7;
    size_t aoff = (size_t)zp * aZp + (size_t)zh * aZh;
    size_t boff = (size_t)zp * bZp + (size_t)zh * bZh;
    ahi += aoff; alo += aoff; bhi += boff; blo += boff;
    size_t cb = (size_t)zp * cZp + (size_t)zh * cZh;
    int m0 = blockIdx.x * 64, n0 = blockIdx.y * 64;
    int tid = threadIdx.x, lane = tid & 63, wid = tid >> 6;
    int wr = wid >> 1, wc = wid & 1, l15 = lane & 15, cg = lane >> 4;
    __shared__ __align__(16) u16 ash[64][40], asl[64][40], bsh[64][40], bsl[64][40];
    f32x4 acc[2][2];
    #pragma unroll
    for (int m = 0; m < 2; m++)
        #pragma unroll
        for (int n = 0; n < 2; n++) acc[m][n] = (f32x4){0.f, 0.f, 0.f, 0.f};
    int rs = tid >> 2, qs = tid & 3;
    for (int k0 = 0; k0 < K; k0 += 32) {
        __syncthreads();
        *(uint4*)&ash[rs][qs * 8] = *(const uint4*)(ahi + (size_t)(m0 + rs) * lda + k0 + qs * 8);
        *(uint4*)&asl[rs][qs * 8] = *(const uint4*)(alo + (size_t)(m0 + rs) * lda + k0 + qs * 8);
        *(uint4*)&bsh[rs][qs * 8] = *(const uint4*)(bhi + (size_t)(n0 + rs) * ldb + k0 + qs * 8);
        *(uint4*)&bsl[rs][qs * 8] = *(const uint4*)(blo + (size_t)(n0 + rs) * ldb + k0 + qs * 8);
        __syncthreads();
        short8 ah[2], al[2], bh[2], bl[2];
        #pragma unroll
        for (int m = 0; m < 2; m++) {
            ah[m] = *(const short8*)&ash[wr * 32 + m * 16 + l15][cg * 8];
            al[m] = *(const short8*)&asl[wr * 32 + m * 16 + l15][cg * 8];
        }
        #pragma unroll
        for (int n = 0; n < 2; n++) {
            bh[n] = *(const short8*)&bsh[wc * 32 + n * 16 + l15][cg * 8];
            bl[n] = *(const short8*)&bsl[wc * 32 + n * 16 + l15][cg * 8];
        }
        #pragma unroll
        for (int m = 0; m < 2; m++)
            #pragma unroll
            for (int n = 0; n < 2; n++) {
                acc[m][n] = __builtin_amdgcn_mfma_f32_16x16x32_bf16(al[m], bh[n], acc[m][n], 0, 0, 0);
                acc[m][n] = __builtin_amdgcn_mfma_f32_16x16x32_bf16(ah[m], bl[n], acc[m][n], 0, 0, 0);
                acc[m][n] = __builtin_amdgcn_mfma_f32_16x16x32_bf16(ah[m], bh[n], acc[m][n], 0, 0, 0);
            }
    }
    #pragma unroll
    for (int m = 0; m < 2; m++)
        #pragma unroll
        for (int n = 0; n < 2; n++)
            #pragma unroll
            for (int r = 0; r < 4; r++) {
                int row = m0 + wr * 32 + m * 16 + cg * 4 + r;
                int col = n0 + wc * 32 + n * 16 + l15;
                float v = acc[m][n][r];
                if (OUT_SPLIT) {
                    u16 hi = f2b(v);
                    ((u16*)c0v)[cb + (size_t)row * ldc + col] = hi;
                    ((u16*)c1v)[cb + (size_t)row * ldc + col] = f2b(v - b2f(hi));
                } else {
                    ((float*)c0v)[cb + (size_t)row * ldc + col] = v;
                }
            }
}

// ---------------- bf16 MFMA GEMM: C[m][n] = alpha * sum_k A[m][k] * BT[n][k] ----------------
template<int OUT_BF16>
__global__ __launch_bounds__(256) void gemm_bt(
    const u16* __restrict__ A, int lda,
    const u16* __restrict__ BT, int ldb,
    void* __restrict__ Cv, int ldc,
    int K, float alpha)
{
    int m0 = blockIdx.x * 64, n0 = blockIdx.y * 64;
    int tid = threadIdx.x, lane = tid & 63, wid = tid >> 6;
    int wr = wid >> 1, wc = wid & 1, l15 = lane & 15, cg = lane >> 4;
    __shared__ __align__(16) u16 as_[64][40];
    __shared__ __align__(16) u16 bs_[64][40];
    f32x4 acc[2][2];
    #pragma unroll
    for (int m = 0; m < 2; m++)
        #pragma unroll
        for (int n = 0; n < 2; n++) acc[m][n] = (f32x4){0.f, 0.f, 0.f, 0.f};
    int rs = tid >> 2, qs = tid & 3;
    for (int k0 = 0; k0 < K; k0 += 32) {
        __syncthreads();
        *(uint4*)&as_[rs][qs * 8] = *(const uint4*)(A  + (size_t)(m0 + rs) * lda + k0 + qs * 8);
        *(uint4*)&bs_[rs][qs * 8] = *(const uint4*)(BT + (size_t)(n0 + rs) * ldb + k0 + qs * 8);
        __syncthreads();
        short8 af[2], bf[2];
        #pragma unroll
        for (int m = 0; m < 2; m++) af[m] = *(const short8*)&as_[wr * 32 + m * 16 + l15][cg * 8];
        #pragma unroll
        for (int n = 0; n < 2; n++) bf[n] = *(const short8*)&bs_[wc * 32 + n * 16 + l15][cg * 8];
        #pragma unroll
        for (int m = 0; m < 2; m++)
            #pragma unroll
            for (int n = 0; n < 2; n++)
                acc[m][n] = __builtin_amdgcn_mfma_f32_16x16x32_bf16(af[m], bf[n], acc[m][n], 0, 0, 0);
    }
    #pragma unroll
    for (int m = 0; m < 2; m++)
        #pragma unroll
        for (int n = 0; n < 2; n++)
            #pragma unroll
            for (int r = 0; r < 4; r++) {
                int row = m0 + wr * 32 + m * 16 + cg * 4 + r;   // C/D: row = cg*4+reg
                int col = n0 + wc * 32 + n * 16 + l15;          //      col = lane&15
                float v = acc[m][n][r] * alpha;
                if (OUT_BF16) ((u16*)Cv)[(size_t)row * ldc + col] = f2b(v);
                else          ((float*)Cv)[(size_t)row * ldc + col] = v;
            }
}

// ---------------- K3: fused two-stage top-16 + softmax. 1 wave per (t,h). ----------------
// Packed key = (sortable_f32 & ~0xFF) | (255-idx): one shfl per butterfly step; exact values kept
// separately for sums/softmax. Tie-break = lowest index (matches lax.top_k stable descending).
__device__ __forceinline__ unsigned packkey(float f, int idx) {
    union { float f; unsigned u; } q; q.f = f;
    unsigned u = q.u;
    unsigned s = u ^ (unsigned)(((int)u >> 31) | 0x80000000);
    return (s & 0xFFFFFF00u) | (unsigned)(255 - idx);
}
__global__ __launch_bounds__(256) void topk_kernel(
    const float* __restrict__ sims, float* __restrict__ fw, int* __restrict__ fidx)
{
    int wid = threadIdx.x >> 6, lane = threadIdx.x & 63;
    int u = blockIdx.x * 4 + wid;     // u = t*8 + h
    int t = u >> 3, h = u & 7;
    __shared__ float lv[4][2][16];
    __shared__ int   li[4][2][16];
    __shared__ float sv[4][16];
    __shared__ int   si[4][16];
    // stage 1: per-p top-16 of 256
    #pragma unroll
    for (int p = 0; p < 2; p++) {
        const float* sp = sims + ((size_t)(p * 2048 + t) * 8 + h) * 256;
        float s[4]; unsigned k4[4];
        #pragma unroll
        for (int j = 0; j < 4; j++) { s[j] = sp[j * 64 + lane]; k4[j] = packkey(s[j], j * 64 + lane); }
        for (int it = 0; it < 16; ++it) {
            unsigned best = k4[0];
            #pragma unroll
            for (int j = 1; j < 4; j++) best = max(best, k4[j]);
            #pragma unroll
            for (int off = 1; off < 64; off <<= 1) {
                unsigned o = (unsigned)__shfl_xor((int)best, off, 64);
                best = max(best, o);
            }
            int idx = 255 - (int)(best & 255u);
            if (lane == (idx & 63)) { lv[wid][p][it] = s[idx >> 6]; k4[idx >> 6] = 0u; }
            if (lane == 0) li[wid][p][it] = idx;
        }
    }
    __syncthreads();
    // stage 2: 16x16 cartesian sums, top-16. candidate cc = i*16+j (i from p0, j from p1)
    float c[4]; unsigned kc[4];
    #pragma unroll
    for (int j = 0; j < 4; j++) {
        int cc = j * 64 + lane;
        c[j] = lv[wid][0][cc >> 4] + lv[wid][1][cc & 15];
        kc[j] = packkey(c[j], cc);
    }
    for (int it = 0; it < 16; ++it) {
        unsigned best = kc[0];
        #pragma unroll
        for (int j = 1; j < 4; j++) best = max(best, kc[j]);
        #pragma unroll
        for (int off = 1; off < 64; off <<= 1) {
            unsigned o = (unsigned)__shfl_xor((int)best, off, 64);
            best = max(best, o);
        }
        int idx = 255 - (int)(best & 255u);
        if (lane == (idx & 63)) { sv[wid][it] = c[idx >> 6]; kc[idx >> 6] = 0u; }
        if (lane == 0) si[wid][it] = idx;
    }
    __syncthreads();
    if (lane < 16) {
        float myv = sv[wid][lane];
        int cc = si[wid][lane];
        float v0 = sv[wid][0];                    // max = first selected (descending)
        float e = __expf(myv - v0);
        float ssum = e;
        #pragma unroll
        for (int off = 1; off < 16; off <<= 1) ssum += __shfl_xor(ssum, off, 16);
        int gi = li[wid][0][cc >> 4] + (li[wid][1][cc & 15] << 8) + (h << 16);
        fw[u * 16 + lane]   = e / ssum;
        fidx[u * 16 + lane] = gi;
    }
}

// ---------------- K4: weighted gather from keys/values tables -> bf16 k,v ----------------
__global__ __launch_bounds__(256) void gather_kernel(
    const float* __restrict__ ktab, const float* __restrict__ vtab,
    const float* __restrict__ fw, const int* __restrict__ fidx,
    u16* __restrict__ kg, u16* __restrict__ vg)
{
    int u = blockIdx.x;              // t*8 + h
    int t = u >> 3, h = u & 7, d = threadIdx.x;
    int b = t >> 10, n = t & 1023;
    float aK = 0.f, aV = 0.f;
    #pragma unroll
    for (int r = 0; r < 16; r++) {
        float w = fw[u * 16 + r];
        size_t row = (size_t)fidx[u * 16 + r];
        aK += w * ktab[row * 256 + d];
        aV += w * vtab[row * 256 + d];
    }
    size_t o = ((size_t)(b * 8 + h) * 1024 + n) * 256 + d;   // [bh][n][d]
    kg[o] = f2b(aK);
    vg[o] = f2b(aV);
}

// ---------------- K5: transpose v [bh][n][d] -> [bh][d][n] ----------------
__global__ __launch_bounds__(256) void vtrans_kernel(const u16* __restrict__ vg, u16* __restrict__ vtg)
{
    int u = blockIdx.x;                  // 16 bh * 4 dtiles * 16 ntiles
    int bh = u >> 6, dt4 = (u >> 4) & 3, nt = u & 15;
    __shared__ float tile[64][65];
    int tid = threadIdx.x;
    #pragma unroll
    for (int p = 0; p < 16; p++) {
        int flat = p * 256 + tid; int rr = flat >> 6, cc = flat & 63;
        tile[rr][cc] = b2f(vg[((size_t)bh * 1024 + nt * 64 + rr) * 256 + dt4 * 64 + cc]);
    }
    __syncthreads();
    #pragma unroll
    for (int p = 0; p < 16; p++) {
        int flat = p * 256 + tid; int od = flat >> 6, on = flat & 63;
        vtg[((size_t)bh * 256 + dt4 * 64 + od) * 1024 + nt * 64 + on] = f2b(tile[on][od]);
    }
}

// ---------------- K6: causal flash attention, 1 wave / block, i-tile=16, kv-chunk=32 ----------------
__global__ __launch_bounds__(64) void attn_kernel(
    const u16* __restrict__ qb, const u16* __restrict__ kg, const u16* __restrict__ vtg,
    u16* __restrict__ attb)
{
    int bid = blockIdx.x;
    int bh = bid >> 6, it = bid & 63;
    int b = bh >> 3, h = bh & 7;
    int i0 = it * 16;
    int lane = threadIdx.x, l15 = lane & 15, cg = lane >> 4;

    __shared__ __align__(16) char ksm[32 * 512];      // K chunk [32][256] bf16, XOR-swizzled 16B groups
    __shared__ __align__(16) u16  vts[256 * 40];      // V^T chunk [256][32] bf16, pad-40 rows
    __shared__ __align__(16) u16  pls[16 * 40];       // P tile [16][32] bf16, pad-40 rows

    short8 qf[8];
    const u16* qrow = qb + (size_t)(b * 1024 + i0 + l15) * 2048 + h * 256 + cg * 8;
    #pragma unroll
    for (int kc = 0; kc < 8; kc++) qf[kc] = *(const short8*)(qrow + kc * 32);

    f32x4 of[16];
    #pragma unroll
    for (int dt = 0; dt < 16; dt++) of[dt] = (f32x4){0.f, 0.f, 0.f, 0.f};
    float m[4] = {-1e30f, -1e30f, -1e30f, -1e30f};
    float l[4] = {0.f, 0.f, 0.f, 0.f};

    int nch = (it >> 1) + 1;
    const u16* kbase = kg  + (size_t)bh * 1024 * 256;
    const u16* vbase = vtg + (size_t)bh * 256 * 1024;

    for (int jc = 0; jc < nch; ++jc) {
        int j0 = jc * 32;
        __syncthreads();
        #pragma unroll
        for (int u = 0; u < 16; ++u) {
            int flat = u * 64 + lane; int r = flat >> 5, g = flat & 31;
            uint4 val = *(const uint4*)(kbase + (size_t)(j0 + r) * 256 + g * 8);
            *(uint4*)(ksm + r * 512 + ((g ^ (r & 7)) << 4)) = val;
        }
        #pragma unroll
        for (int u = 0; u < 16; ++u) {
            int flat = u * 64 + lane; int d = flat >> 2, g = flat & 3;
            uint4 val = *(const uint4*)(vbase + (size_t)d * 1024 + j0 + g * 8);
            *(uint4*)((char*)vts + d * 80 + g * 16) = val;
        }
        __syncthreads();

        f32x4 c0 = (f32x4){0.f, 0.f, 0.f, 0.f};
        f32x4 c1 = (f32x4){0.f, 0.f, 0.f, 0.f};
        #pragma unroll
        for (int kc = 0; kc < 8; kc++) {
            int g = kc * 4 + cg;
            short8 b0 = *(const short8*)(ksm + l15 * 512        + ((g ^ (l15 & 7)) << 4));
            short8 b1 = *(const short8*)(ksm + (16 + l15) * 512 + ((g ^ ((16 + l15) & 7)) << 4));
            c0 = __builtin_amdgcn_mfma_f32_16x16x32_bf16(qf[kc], b0, c0, 0, 0, 0);
            c1 = __builtin_amdgcn_mfma_f32_16x16x32_bf16(qf[kc], b1, c1, 0, 0, 0);
        }
        if (jc == nch - 1) {
            #pragma unroll
            for (int r = 0; r < 4; r++) {
                int ig = i0 + cg * 4 + r;
                if (j0 + l15 > ig)      c0[r] = -1e30f;
                if (j0 + 16 + l15 > ig) c1[r] = -1e30f;
            }
        }
        float es[4];
        #pragma unroll
        for (int r = 0; r < 4; r++) {
            float mr = fmaxf(c0[r], c1[r]);
            for (int off = 1; off < 16; off <<= 1) mr = fmaxf(mr, __shfl_xor(mr, off, 16));
            float mn = fmaxf(m[r], mr);
            float p0 = __expf(c0[r] - mn), p1 = __expf(c1[r] - mn);
            c0[r] = p0; c1[r] = p1;
            float rsum = p0 + p1;
            for (int off = 1; off < 16; off <<= 1) rsum += __shfl_xor(rsum, off, 16);
            es[r] = __expf(m[r] - mn);
            l[r] = l[r] * es[r] + rsum;
            m[r] = mn;
        }
        #pragma unroll
        for (int r = 0; r < 4; r++) {
            int row = cg * 4 + r;
            pls[row * 40 + l15]      = f2b(c0[r]);
            pls[row * 40 + 16 + l15] = f2b(c1[r]);
        }
        #pragma unroll
        for (int dt = 0; dt < 16; dt++)
            #pragma unroll
            for (int r = 0; r < 4; r++) of[dt][r] *= es[r];
        __syncthreads();
        short8 pa = *(const short8*)((char*)pls + l15 * 80 + cg * 16);
        #pragma unroll
        for (int dt = 0; dt < 16; ++dt) {
            short8 bv = *(const short8*)((char*)vts + (dt * 16 + l15) * 80 + cg * 16);
            of[dt] = __builtin_amdgcn_mfma_f32_16x16x32_bf16(pa, bv, of[dt], 0, 0, 0);
        }
    }
    float rl[4];
    #pragma unroll
    for (int r = 0; r < 4; r++) rl[r] = 1.f / l[r];
    u16* orow = attb + (size_t)(b * 1024 + i0) * 2048 + h * 256;
    #pragma unroll
    for (int dt = 0; dt < 16; dt++)
        #pragma unroll
        for (int r = 0; r < 4; r++)
            orow[(size_t)(cg * 4 + r) * 2048 + dt * 16 + l15] = f2b(of[dt][r] * rl[r]);
}

// ---------------- launcher ----------------
extern "C" void kernel_launch(void* const* d_in, const int* in_sizes, int n_in,
                              void* d_out, int out_size, void* d_ws, size_t ws_size,
                              hipStream_t stream) {
    (void)in_sizes; (void)n_in; (void)out_size; (void)ws_size;
    const float* x    = (const float*)d_in[0];
    const float* wqpk = (const float*)d_in[1];
    const float* pkk  = (const float*)d_in[2];
    const float* wq   = (const float*)d_in[3];
    const float* ktab = (const float*)d_in[4];
    const float* vtab = (const float*)d_in[5];
    const float* wo   = (const float*)d_in[6];
    float* out = (float*)d_out;

    char* w = (char*)d_ws;
    const size_t MB = 1u << 20;
    u16*   xhi      = (u16*)(w + 0 * MB);    // [2048][256]
    u16*   xlo      = (u16*)(w + 1 * MB);
    u16*   wqpk_thi = (u16*)(w + 2 * MB);    // [2048][256]
    u16*   wqpk_tlo = (u16*)(w + 3 * MB);
    u16*   wq_t     = (u16*)(w + 4 * MB);    // [2048][256]
    u16*   wo_t     = (u16*)(w + 5 * MB);    // [256][2048]
    u16*   pkthi    = (u16*)(w + 6 * MB);    // [2][8][256][128]
    u16*   pktlo    = (u16*)(w + 7 * MB);
    u16*   qpk_hi   = (u16*)(w + 8 * MB);    // [2048][2048] (8 MB)
    u16*   qpk_lo   = (u16*)(w + 16 * MB);
    u16*   q_b      = (u16*)(w + 24 * MB);   // [2048][2048], pre-scaled by 1/16
    float* sims     = (float*)(w + 32 * MB); // [2][2048][8][256] f32 (32 MB), dead after topk
    u16*   kg       = (u16*)(w + 32 * MB);   // [16][1024][256] (8 MB), overlays dead sims
    u16*   vg       = (u16*)(w + 40 * MB);
    u16*   vtg      = (u16*)(w + 48 * MB);   // [16][256][1024]
    u16*   attb     = (u16*)(w + 56 * MB);   // [2048][2048]
    float* fw       = (float*)(w + 64 * MB); // [16384][16]
    int*   fidx     = (int*)(w + 65 * MB);

    prep_elem<<<dim3(256, 2), 256, 0, stream>>>(x, pkk, xhi, xlo, pkthi, pktlo);
    trans_kernel<<<dim3(128, 3), 256, 0, stream>>>(wqpk, wq, wo, wqpk_thi, wqpk_tlo, wq_t, wo_t);
    // qpk = x @ Wq_pk  (bf16x3, split output)
    gemm_x3<1><<<dim3(32, 32, 1), 256, 0, stream>>>(xhi, xlo, 0, 0, 256,
                                                    wqpk_thi, wqpk_tlo, 0, 0, 256,
                                                    qpk_hi, qpk_lo, 0, 0, 2048, 256);
    // sims[p][t][h][key] = qpk[t,(p,h,:)] . pk_keys[p,key,h,:]  (bf16x3, f32 out), z = p*8+h
    gemm_x3<0><<<dim3(32, 4, 16), 256, 0, stream>>>(qpk_hi, qpk_lo, 1024, 128, 2048,
                                                    pkthi, pktlo, 262144, 32768, 128,
                                                    sims, nullptr, 4194304, 256, 2048, 128);
    // q = (x @ Wq) * DIM^-0.5  (bf16 MFMA)
    gemm_bt<1><<<dim3(32, 32, 1), 256, 0, stream>>>(xhi, 256, wq_t, 256, q_b, 2048, 256, 0.0625f);
    topk_kernel<<<4096, 256, 0, stream>>>(sims, fw, fidx);
    gather_kernel<<<16384, 256, 0, stream>>>(ktab, vtab, fw, fidx, kg, vg);
    vtrans_kernel<<<1024, 256, 0, stream>>>(vg, vtg);
    attn_kernel<<<1024, 64, 0, stream>>>(q_b, kg, vtg, attb);
    // out = att @ Wo  (f32 out)
    gemm_bt<0><<<dim3(32, 4, 1), 256, 0, stream>>>(attb, 2048, wo_t, 2048, out, 256, 2048, 1.f);
}

// Round 4
// 297.534 us; speedup vs baseline: 2.1337x; 1.8574x over previous
//
#include <hip/hip_runtime.h>

typedef unsigned short u16;
typedef __attribute__((ext_vector_type(8))) short short8;   // 8 x bf16 (4 VGPRs) MFMA A/B frag
typedef __attribute__((ext_vector_type(4))) float f32x4;    // MFMA C/D frag

__device__ __forceinline__ u16 f2b(float f) {               // f32 -> bf16 RNE
    union { float f; unsigned u; } v; v.f = f;
    unsigned u = v.u;
    u += 0x7fffu + ((u >> 16) & 1u);
    return (u16)(u >> 16);
}
__device__ __forceinline__ float b2f(u16 s) {
    union { unsigned u; float f; } v; v.u = ((unsigned)s) << 16;
    return v.f;
}

// Sizes: B=2, N=1024, T=2048 tokens, H=8, D=256, DK=128, NK=256 keys, TOPK=16, NUM_KV=65536.

// ---------------- K0: elementwise bf16 hi/lo splits (x, pk_keys-permuted) ----------------
__global__ __launch_bounds__(256) void prep_elem(
    const float* __restrict__ x, const float* __restrict__ pkk,
    u16* __restrict__ xhi, u16* __restrict__ xlo,
    u16* __restrict__ pkthi, u16* __restrict__ pktlo)
{
    int job = blockIdx.y;
    for (int i = blockIdx.x * 256 + threadIdx.x; i < 524288; i += 256 * 256) {
        if (job == 0) {
            float v = x[i];
            u16 hi = f2b(v); xhi[i] = hi; xlo[i] = f2b(v - b2f(hi));
        } else {
            // pkt[p][h][key][d] = pk_keys[p][key][h][d]; d innermost both sides -> coalesced
            int d = i & 127, key = (i >> 7) & 255, h = (i >> 15) & 7, p = i >> 18;
            float v = pkk[(((p << 8) + key) * 8 + h) * 128 + d];
            u16 hi = f2b(v); pkthi[i] = hi; pktlo[i] = f2b(v - b2f(hi));
        }
    }
}

// ---------------- K1: tiled 64x64 transposes, coalesced both sides ----------------
__global__ __launch_bounds__(256) void trans_kernel(
    const float* __restrict__ wqpk, const float* __restrict__ wq, const float* __restrict__ wo,
    u16* __restrict__ wqpk_thi, u16* __restrict__ wqpk_tlo,
    u16* __restrict__ wq_t, u16* __restrict__ wo_t)
{
    int job = blockIdx.y, tile = blockIdx.x, tid = threadIdx.x;
    const float* in = (job == 0) ? wqpk : (job == 1) ? wq : wo;
    int R = (job == 2) ? 2048 : 256;
    int C = (job == 2) ? 256 : 2048;
    int CT = C >> 6;
    int tr = tile / CT, tc = tile % CT;
    __shared__ float t[64][65];
    #pragma unroll
    for (int p = 0; p < 16; p++) {
        int row = p * 4 + (tid >> 6), col = tid & 63;
        t[row][col] = in[(size_t)(tr * 64 + row) * C + tc * 64 + col];
    }
    __syncthreads();
    #pragma unroll
    for (int p = 0; p < 16; p++) {
        int row = p * 4 + (tid >> 6), col = tid & 63;
        float v = t[col][row];
        size_t o = (size_t)(tc * 64 + row) * R + tr * 64 + col;
        if (job == 0) { u16 hi = f2b(v); wqpk_thi[o] = hi; wqpk_tlo[o] = f2b(v - b2f(hi)); }
        else if (job == 1) wq_t[o] = f2b(v);
        else               wo_t[o] = f2b(v);
    }
}

// ---------------- bf16x3 MFMA GEMM (near-f32 exact): C = (Ahi+Alo)(Bhi+Blo)^T, drop lo*lo ----------------
template<int OUT_SPLIT>
__global__ __launch_bounds__(256) void gemm_x3(
    const u16* __restrict__ ahi, const u16* __restrict__ alo, int aZp, int aZh, int lda,
    const u16* __restrict__ bhi, const u16* __restrict__ blo, int bZp, int bZh, int ldb,
    void* __restrict__ c0v, void* __restrict__ c1v, int cZp, int cZh, int ldc, int K)
{
    int z = blockIdx.z, zp = z >> 3, zh = z & 7;
    size_t aoff = (size_t)zp * aZp + (size_t)zh * aZh;
    size_t boff = (size_t)zp * bZp + (size_t)zh * bZh;
    ahi += aoff; alo += aoff; bhi += boff; blo += boff;
    size_t cb = (size_t)zp * cZp + (size_t)zh * cZh;
    int m0 = blockIdx.x * 64, n0 = blockIdx.y * 64;
    int tid = threadIdx.x, lane = tid & 63, wid = tid >> 6;
    int wr = wid >> 1, wc = wid & 1, l15 = lane & 15, cg = lane >> 4;
    __shared__ __align__(16) u16 ash[64][40], asl[64][40], bsh[64][40], bsl[64][40];
    f32x4 acc[2][2];
    #pragma unroll
    for (int m = 0; m < 2; m++)
        #pragma unroll
        for (int n = 0; n < 2; n++) acc[m][n] = (f32x4){0.f, 0.f, 0.f, 0.f};
    int rs = tid >> 2, qs = tid & 3;
    for (int k0 = 0; k0 < K; k0 += 32) {
        __syncthreads();
        *(uint4*)&ash[rs][qs * 8] = *(const uint4*)(ahi + (size_t)(m0 + rs) * lda + k0 + qs * 8);
        *(uint4*)&asl[rs][qs * 8] = *(const uint4*)(alo + (size_t)(m0 + rs) * lda + k0 + qs * 8);
        *(uint4*)&bsh[rs][qs * 8] = *(const uint4*)(bhi + (size_t)(n0 + rs) * ldb + k0 + qs * 8);
        *(uint4*)&bsl[rs][qs * 8] = *(const uint4*)(blo + (size_t)(n0 + rs) * ldb + k0 + qs * 8);
        __syncthreads();
        short8 ah[2], al[2], bh[2], bl[2];
        #pragma unroll
        for (int m = 0; m < 2; m++) {
            ah[m] = *(const short8*)&ash[wr * 32 + m * 16 + l15][cg * 8];
            al[m] = *(const short8*)&asl[wr * 32 + m * 16 + l15][cg * 8];
        }
        #pragma unroll
        for (int n = 0; n < 2; n++) {
            bh[n] = *(const short8*)&bsh[wc * 32 + n * 16 + l15][cg * 8];
            bl[n] = *(const short8*)&bsl[wc * 32 + n * 16 + l15][cg * 8];
        }
        #pragma unroll
        for (int m = 0; m < 2; m++)
            #pragma unroll
            for (int n = 0; n < 2; n++) {
                acc[m][n] = __builtin_amdgcn_mfma_f32_16x16x32_bf16(al[m], bh[n], acc[m][n], 0, 0, 0);
                acc[m][n] = __builtin_amdgcn_mfma_f32_16x16x32_bf16(ah[m], bl[n], acc[m][n], 0, 0, 0);
                acc[m][n] = __builtin_amdgcn_mfma_f32_16x16x32_bf16(ah[m], bh[n], acc[m][n], 0, 0, 0);
            }
    }
    #pragma unroll
    for (int m = 0; m < 2; m++)
        #pragma unroll
        for (int n = 0; n < 2; n++)
            #pragma unroll
            for (int r = 0; r < 4; r++) {
                int row = m0 + wr * 32 + m * 16 + cg * 4 + r;
                int col = n0 + wc * 32 + n * 16 + l15;
                float v = acc[m][n][r];
                if (OUT_SPLIT) {
                    u16 hi = f2b(v);
                    ((u16*)c0v)[cb + (size_t)row * ldc + col] = hi;
                    ((u16*)c1v)[cb + (size_t)row * ldc + col] = f2b(v - b2f(hi));
                } else {
                    ((float*)c0v)[cb + (size_t)row * ldc + col] = v;
                }
            }
}

// ---------------- bf16 MFMA GEMM: C[m][n] = alpha * sum_k A[m][k] * BT[n][k] ----------------
template<int OUT_BF16>
__global__ __launch_bounds__(256) void gemm_bt(
    const u16* __restrict__ A, int lda,
    const u16* __restrict__ BT, int ldb,
    void* __restrict__ Cv, int ldc,
    int K, float alpha)
{
    int m0 = blockIdx.x * 64, n0 = blockIdx.y * 64;
    int tid = threadIdx.x, lane = tid & 63, wid = tid >> 6;
    int wr = wid >> 1, wc = wid & 1, l15 = lane & 15, cg = lane >> 4;
    __shared__ __align__(16) u16 as_[64][40];
    __shared__ __align__(16) u16 bs_[64][40];
    f32x4 acc[2][2];
    #pragma unroll
    for (int m = 0; m < 2; m++)
        #pragma unroll
        for (int n = 0; n < 2; n++) acc[m][n] = (f32x4){0.f, 0.f, 0.f, 0.f};
    int rs = tid >> 2, qs = tid & 3;
    for (int k0 = 0; k0 < K; k0 += 32) {
        __syncthreads();
        *(uint4*)&as_[rs][qs * 8] = *(const uint4*)(A  + (size_t)(m0 + rs) * lda + k0 + qs * 8);
        *(uint4*)&bs_[rs][qs * 8] = *(const uint4*)(BT + (size_t)(n0 + rs) * ldb + k0 + qs * 8);
        __syncthreads();
        short8 af[2], bf[2];
        #pragma unroll
        for (int m = 0; m < 2; m++) af[m] = *(const short8*)&as_[wr * 32 + m * 16 + l15][cg * 8];
        #pragma unroll
        for (int n = 0; n < 2; n++) bf[n] = *(const short8*)&bs_[wc * 32 + n * 16 + l15][cg * 8];
        #pragma unroll
        for (int m = 0; m < 2; m++)
            #pragma unroll
            for (int n = 0; n < 2; n++)
                acc[m][n] = __builtin_amdgcn_mfma_f32_16x16x32_bf16(af[m], bf[n], acc[m][n], 0, 0, 0);
    }
    #pragma unroll
    for (int m = 0; m < 2; m++)
        #pragma unroll
        for (int n = 0; n < 2; n++)
            #pragma unroll
            for (int r = 0; r < 4; r++) {
                int row = m0 + wr * 32 + m * 16 + cg * 4 + r;   // C/D: row = cg*4+reg
                int col = n0 + wc * 32 + n * 16 + l15;          //      col = lane&15
                float v = acc[m][n][r] * alpha;
                if (OUT_BF16) ((u16*)Cv)[(size_t)row * ldc + col] = f2b(v);
                else          ((float*)Cv)[(size_t)row * ldc + col] = v;
            }
}

// ---------------- K3: fused two-stage top-16 + softmax. 1 wave per (t,h). ----------------
__device__ __forceinline__ unsigned packkey(float f, int idx) {
    union { float f; unsigned u; } q; q.f = f;
    unsigned u = q.u;
    unsigned s = u ^ (unsigned)(((int)u >> 31) | 0x80000000);
    return (s & 0xFFFFFF00u) | (unsigned)(255 - idx);
}
__global__ __launch_bounds__(256) void topk_kernel(
    const float* __restrict__ sims, float* __restrict__ fw, int* __restrict__ fidx)
{
    int wid = threadIdx.x >> 6, lane = threadIdx.x & 63;
    int u = blockIdx.x * 4 + wid;     // u = t*8 + h
    int t = u >> 3, h = u & 7;
    __shared__ float lv[4][2][16];
    __shared__ int   li[4][2][16];
    __shared__ float sv[4][16];
    __shared__ int   si[4][16];
    #pragma unroll
    for (int p = 0; p < 2; p++) {
        const float* sp = sims + ((size_t)(p * 2048 + t) * 8 + h) * 256;
        float s[4]; unsigned k4[4];
        #pragma unroll
        for (int j = 0; j < 4; j++) { s[j] = sp[j * 64 + lane]; k4[j] = packkey(s[j], j * 64 + lane); }
        for (int it = 0; it < 16; ++it) {
            unsigned best = k4[0];
            #pragma unroll
            for (int j = 1; j < 4; j++) best = max(best, k4[j]);
            #pragma unroll
            for (int off = 1; off < 64; off <<= 1) {
                unsigned o = (unsigned)__shfl_xor((int)best, off, 64);
                best = max(best, o);
            }
            int idx = 255 - (int)(best & 255u);
            if (lane == (idx & 63)) { lv[wid][p][it] = s[idx >> 6]; k4[idx >> 6] = 0u; }
            if (lane == 0) li[wid][p][it] = idx;
        }
    }
    __syncthreads();
    float c[4]; unsigned kc[4];
    #pragma unroll
    for (int j = 0; j < 4; j++) {
        int cc = j * 64 + lane;
        c[j] = lv[wid][0][cc >> 4] + lv[wid][1][cc & 15];
        kc[j] = packkey(c[j], cc);
    }
    for (int it = 0; it < 16; ++it) {
        unsigned best = kc[0];
        #pragma unroll
        for (int j = 1; j < 4; j++) best = max(best, kc[j]);
        #pragma unroll
        for (int off = 1; off < 64; off <<= 1) {
            unsigned o = (unsigned)__shfl_xor((int)best, off, 64);
            best = max(best, o);
        }
        int idx = 255 - (int)(best & 255u);
        if (lane == (idx & 63)) { sv[wid][it] = c[idx >> 6]; kc[idx >> 6] = 0u; }
        if (lane == 0) si[wid][it] = idx;
    }
    __syncthreads();
    if (lane < 16) {
        float myv = sv[wid][lane];
        int cc = si[wid][lane];
        float v0 = sv[wid][0];
        float e = __expf(myv - v0);
        float ssum = e;
        #pragma unroll
        for (int off = 1; off < 16; off <<= 1) ssum += __shfl_xor(ssum, off, 16);
        int gi = li[wid][0][cc >> 4] + (li[wid][1][cc & 15] << 8) + (h << 16);
        fw[u * 16 + lane]   = e / ssum;
        fidx[u * 16 + lane] = gi;
    }
}

// ---------------- K4: weighted gather from keys/values tables -> bf16 k,v ----------------
__global__ __launch_bounds__(256) void gather_kernel(
    const float* __restrict__ ktab, const float* __restrict__ vtab,
    const float* __restrict__ fw, const int* __restrict__ fidx,
    u16* __restrict__ kg, u16* __restrict__ vg)
{
    int u = blockIdx.x;              // t*8 + h
    int t = u >> 3, h = u & 7, d = threadIdx.x;
    int b = t >> 10, n = t & 1023;
    float aK = 0.f, aV = 0.f;
    #pragma unroll
    for (int r = 0; r < 16; r++) {
        float w = fw[u * 16 + r];
        size_t row = (size_t)fidx[u * 16 + r];
        aK += w * ktab[row * 256 + d];
        aV += w * vtab[row * 256 + d];
    }
    size_t o = ((size_t)(b * 8 + h) * 1024 + n) * 256 + d;   // [bh][n][d]
    kg[o] = f2b(aK);
    vg[o] = f2b(aV);
}

// ---------------- K5: transpose v [bh][n][d] -> [bh][d][n] ----------------
__global__ __launch_bounds__(256) void vtrans_kernel(const u16* __restrict__ vg, u16* __restrict__ vtg)
{
    int u = blockIdx.x;                  // 16 bh * 4 dtiles * 16 ntiles
    int bh = u >> 6, dt4 = (u >> 4) & 3, nt = u & 15;
    __shared__ float tile[64][65];
    int tid = threadIdx.x;
    #pragma unroll
    for (int p = 0; p < 16; p++) {
        int flat = p * 256 + tid; int rr = flat >> 6, cc = flat & 63;
        tile[rr][cc] = b2f(vg[((size_t)bh * 1024 + nt * 64 + rr) * 256 + dt4 * 64 + cc]);
    }
    __syncthreads();
    #pragma unroll
    for (int p = 0; p < 16; p++) {
        int flat = p * 256 + tid; int od = flat >> 6, on = flat & 63;
        vtg[((size_t)bh * 256 + dt4 * 64 + od) * 1024 + nt * 64 + on] = f2b(tile[on][od]);
    }
}

// ---------------- K6: causal flash attention, 4 waves / block, Q-tile 64, kv-chunk 64 ----------------
// Grid: 16 bh x 16 i-tiles = 256 blocks, 256 threads. Wave w owns q-rows i0+w*16..+15.
// K LDS [64][512B] swizzle g^(r&7) on 16B groups; V^T LDS [256][128B] swizzle g^(d&7);
// per-wave P tile [16][72] u16 (rows 144B, 16B-aligned).
__global__ __launch_bounds__(256) void attn_kernel(
    const u16* __restrict__ qb, const u16* __restrict__ kg, const u16* __restrict__ vtg,
    u16* __restrict__ attb)
{
    int bid = blockIdx.x;
    int bh = bid >> 4, it = bid & 15;
    int b = bh >> 3, h = bh & 7;
    int i0 = it * 64;
    int tid = threadIdx.x, lane = tid & 63, wid = tid >> 6;
    int l15 = lane & 15, cg = lane >> 4;

    __shared__ __align__(16) char ksm[64 * 512];      // K chunk [64][256] bf16, swizzled
    __shared__ __align__(16) char vts[256 * 128];     // V^T chunk [256][64] bf16, swizzled
    __shared__ __align__(16) u16  pls[4][16][72];     // per-wave P [16 rows][64 cols], pad 72

    // per-wave Q A-fragments: qf[kc], rows i0 + wid*16 + l15
    short8 qf[8];
    const u16* qrow = qb + (size_t)(b * 1024 + i0 + wid * 16 + l15) * 2048 + h * 256 + cg * 8;
    #pragma unroll
    for (int kc = 0; kc < 8; kc++) qf[kc] = *(const short8*)(qrow + kc * 32);

    f32x4 of[16];
    #pragma unroll
    for (int dt = 0; dt < 16; dt++) of[dt] = (f32x4){0.f, 0.f, 0.f, 0.f};
    float m[4] = {-1e30f, -1e30f, -1e30f, -1e30f};
    float l[4] = {0.f, 0.f, 0.f, 0.f};

    int nch = it + 1;
    const u16* kbase = kg  + (size_t)bh * 1024 * 256;
    const u16* vbase = vtg + (size_t)bh * 256 * 1024;

    for (int jc = 0; jc < nch; ++jc) {
        int j0 = jc * 64;
        __syncthreads();
        // stage K: 64 rows x 32 groups of 16B, 2048 ops / 256 threads
        #pragma unroll
        for (int u8 = 0; u8 < 8; ++u8) {
            int flat = u8 * 256 + tid; int r = flat >> 5, g = flat & 31;
            uint4 val = *(const uint4*)(kbase + (size_t)(j0 + r) * 256 + g * 8);
            *(uint4*)(ksm + r * 512 + ((g ^ (r & 7)) << 4)) = val;
        }
        // stage V^T: 256 rows x 8 groups of 16B
        #pragma unroll
        for (int u8 = 0; u8 < 8; ++u8) {
            int flat = u8 * 256 + tid; int d = flat >> 3, g = flat & 7;
            uint4 val = *(const uint4*)(vbase + (size_t)d * 1024 + j0 + g * 8);
            *(uint4*)(vts + d * 128 + ((g ^ (d & 7)) << 4)) = val;
        }
        __syncthreads();

        // QK^T: S[16 rows][64 cols] = 4 col-tiles
        f32x4 c[4];
        #pragma unroll
        for (int ct = 0; ct < 4; ct++) c[ct] = (f32x4){0.f, 0.f, 0.f, 0.f};
        #pragma unroll
        for (int kc = 0; kc < 8; kc++) {
            int g = kc * 4 + cg;
            #pragma unroll
            for (int ct = 0; ct < 4; ct++) {
                int r = ct * 16 + l15;
                short8 bfrag = *(const short8*)(ksm + r * 512 + ((g ^ (r & 7)) << 4));
                c[ct] = __builtin_amdgcn_mfma_f32_16x16x32_bf16(qf[kc], bfrag, c[ct], 0, 0, 0);
            }
        }
        // causal mask: only the diagonal chunk (jc == it, j0 == i0)
        if (jc == it) {
            #pragma unroll
            for (int ct = 0; ct < 4; ct++)
                #pragma unroll
                for (int rr = 0; rr < 4; rr++)
                    if (ct * 16 + l15 > wid * 16 + cg * 4 + rr) c[ct][rr] = -1e30f;
        }
        // online softmax per row (rows live as reg rr across 16-lane groups)
        float es[4];
        #pragma unroll
        for (int rr = 0; rr < 4; rr++) {
            float mr = fmaxf(fmaxf(c[0][rr], c[1][rr]), fmaxf(c[2][rr], c[3][rr]));
            #pragma unroll
            for (int off = 1; off < 16; off <<= 1) mr = fmaxf(mr, __shfl_xor(mr, off, 16));
            float mn = fmaxf(m[rr], mr);
            float rsum = 0.f;
            #pragma unroll
            for (int ct = 0; ct < 4; ct++) {
                float p = __expf(c[ct][rr] - mn);
                c[ct][rr] = p; rsum += p;
            }
            #pragma unroll
            for (int off = 1; off < 16; off <<= 1) rsum += __shfl_xor(rsum, off, 16);
            es[rr] = __expf(m[rr] - mn);
            l[rr] = l[rr] * es[rr] + rsum;
            m[rr] = mn;
        }
        // P -> per-wave LDS (C layout row=cg*4+rr, col=ct*16+l15)
        #pragma unroll
        for (int rr = 0; rr < 4; rr++)
            #pragma unroll
            for (int ct = 0; ct < 4; ct++)
                pls[wid][cg * 4 + rr][ct * 16 + l15] = f2b(c[ct][rr]);
        // rescale O
        #pragma unroll
        for (int dt = 0; dt < 16; dt++)
            #pragma unroll
            for (int rr = 0; rr < 4; rr++) of[dt][rr] *= es[rr];
        // PV: A = P[16][64] (2 k-steps), B from swizzled V^T
        short8 pa0 = *(const short8*)&pls[wid][l15][cg * 8];
        short8 pa1 = *(const short8*)&pls[wid][l15][32 + cg * 8];
        #pragma unroll
        for (int dt = 0; dt < 16; ++dt) {
            int row = dt * 16 + l15;
            short8 b0 = *(const short8*)(vts + row * 128 + ((cg       ^ (row & 7)) << 4));
            short8 b1 = *(const short8*)(vts + row * 128 + (((4 + cg) ^ (row & 7)) << 4));
            of[dt] = __builtin_amdgcn_mfma_f32_16x16x32_bf16(pa0, b0, of[dt], 0, 0, 0);
            of[dt] = __builtin_amdgcn_mfma_f32_16x16x32_bf16(pa1, b1, of[dt], 0, 0, 0);
        }
    }
    // epilogue: att[t][h*256+d] = O/l
    float rl[4];
    #pragma unroll
    for (int rr = 0; rr < 4; rr++) rl[rr] = 1.f / l[rr];
    u16* orow = attb + (size_t)(b * 1024 + i0 + wid * 16) * 2048 + h * 256;
    #pragma unroll
    for (int dt = 0; dt < 16; dt++)
        #pragma unroll
        for (int rr = 0; rr < 4; rr++)
            orow[(size_t)(cg * 4 + rr) * 2048 + dt * 16 + l15] = f2b(of[dt][rr] * rl[rr]);
}

// ---------------- launcher ----------------
extern "C" void kernel_launch(void* const* d_in, const int* in_sizes, int n_in,
                              void* d_out, int out_size, void* d_ws, size_t ws_size,
                              hipStream_t stream) {
    (void)in_sizes; (void)n_in; (void)out_size; (void)ws_size;
    const float* x    = (const float*)d_in[0];
    const float* wqpk = (const float*)d_in[1];
    const float* pkk  = (const float*)d_in[2];
    const float* wq   = (const float*)d_in[3];
    const float* ktab = (const float*)d_in[4];
    const float* vtab = (const float*)d_in[5];
    const float* wo   = (const float*)d_in[6];
    float* out = (float*)d_out;

    char* w = (char*)d_ws;
    const size_t MB = 1u << 20;
    u16*   xhi      = (u16*)(w + 0 * MB);    // [2048][256]
    u16*   xlo      = (u16*)(w + 1 * MB);
    u16*   wqpk_thi = (u16*)(w + 2 * MB);    // [2048][256]
    u16*   wqpk_tlo = (u16*)(w + 3 * MB);
    u16*   wq_t     = (u16*)(w + 4 * MB);    // [2048][256]
    u16*   wo_t     = (u16*)(w + 5 * MB);    // [256][2048]
    u16*   pkthi    = (u16*)(w + 6 * MB);    // [2][8][256][128]
    u16*   pktlo    = (u16*)(w + 7 * MB);
    u16*   qpk_hi   = (u16*)(w + 8 * MB);    // [2048][2048] (8 MB)
    u16*   qpk_lo   = (u16*)(w + 16 * MB);
    u16*   q_b      = (u16*)(w + 24 * MB);   // [2048][2048], pre-scaled by 1/16
    float* sims     = (float*)(w + 32 * MB); // [2][2048][8][256] f32 (32 MB), dead after topk
    u16*   kg       = (u16*)(w + 32 * MB);   // [16][1024][256] (8 MB), overlays dead sims
    u16*   vg       = (u16*)(w + 40 * MB);
    u16*   vtg      = (u16*)(w + 48 * MB);   // [16][256][1024]
    u16*   attb     = (u16*)(w + 56 * MB);   // [2048][2048]
    float* fw       = (float*)(w + 64 * MB); // [16384][16]
    int*   fidx     = (int*)(w + 65 * MB);

    prep_elem<<<dim3(256, 2), 256, 0, stream>>>(x, pkk, xhi, xlo, pkthi, pktlo);
    trans_kernel<<<dim3(128, 3), 256, 0, stream>>>(wqpk, wq, wo, wqpk_thi, wqpk_tlo, wq_t, wo_t);
    // qpk = x @ Wq_pk  (bf16x3, split output)
    gemm_x3<1><<<dim3(32, 32, 1), 256, 0, stream>>>(xhi, xlo, 0, 0, 256,
                                                    wqpk_thi, wqpk_tlo, 0, 0, 256,
                                                    qpk_hi, qpk_lo, 0, 0, 2048, 256);
    // sims[p][t][h][key] = qpk[t,(p,h,:)] . pk_keys[p,key,h,:]  (bf16x3, f32 out), z = p*8+h
    gemm_x3<0><<<dim3(32, 4, 16), 256, 0, stream>>>(qpk_hi, qpk_lo, 1024, 128, 2048,
                                                    pkthi, pktlo, 262144, 32768, 128,
                                                    sims, nullptr, 4194304, 256, 2048, 128);
    // q = (x @ Wq) * DIM^-0.5  (bf16 MFMA)
    gemm_bt<1><<<dim3(32, 32, 1), 256, 0, stream>>>(xhi, 256, wq_t, 256, q_b, 2048, 256, 0.0625f);
    topk_kernel<<<4096, 256, 0, stream>>>(sims, fw, fidx);
    gather_kernel<<<16384, 256, 0, stream>>>(ktab, vtab, fw, fidx, kg, vg);
    vtrans_kernel<<<1024, 256, 0, stream>>>(vg, vtg);
    attn_kernel<<<256, 256, 0, stream>>>(q_b, kg, vtg, attb);
    // out = att @ Wo  (f32 out)
    gemm_bt<0><<<dim3(32, 4, 1), 256, 0, stream>>>(attb, 2048, wo_t, 2048, out, 256, 2048, 1.f);
}

// Round 5
// 282.700 us; speedup vs baseline: 2.2457x; 1.0525x over previous
//
#include <hip/hip_runtime.h>

typedef unsigned short u16;
typedef __attribute__((ext_vector_type(8))) short short8;   // 8 x bf16 (4 VGPRs) MFMA A/B frag
typedef __attribute__((ext_vector_type(4))) float f32x4;    // MFMA C/D frag

__device__ __forceinline__ u16 f2b(float f) {               // f32 -> bf16 RNE
    union { float f; unsigned u; } v; v.f = f;
    unsigned u = v.u;
    u += 0x7fffu + ((u >> 16) & 1u);
    return (u16)(u >> 16);
}
__device__ __forceinline__ float b2f(u16 s) {
    union { unsigned u; float f; } v; v.u = ((unsigned)s) << 16;
    return v.f;
}

// Sizes: B=2, N=1024, T=2048 tokens, H=8, D=256, DK=128, NK=256 keys, TOPK=16, NUM_KV=65536.

// ---------------- K0: elementwise bf16 hi/lo splits (x, pk_keys-permuted) ----------------
__global__ __launch_bounds__(256) void prep_elem(
    const float* __restrict__ x, const float* __restrict__ pkk,
    u16* __restrict__ xhi, u16* __restrict__ xlo,
    u16* __restrict__ pkthi, u16* __restrict__ pktlo)
{
    int job = blockIdx.y;
    for (int i = blockIdx.x * 256 + threadIdx.x; i < 524288; i += 256 * 256) {
        if (job == 0) {
            float v = x[i];
            u16 hi = f2b(v); xhi[i] = hi; xlo[i] = f2b(v - b2f(hi));
        } else {
            // pkt[p][h][key][d] = pk_keys[p][key][h][d]; d innermost both sides -> coalesced
            int d = i & 127, key = (i >> 7) & 255, h = (i >> 15) & 7, p = i >> 18;
            float v = pkk[(((p << 8) + key) * 8 + h) * 128 + d];
            u16 hi = f2b(v); pkthi[i] = hi; pktlo[i] = f2b(v - b2f(hi));
        }
    }
}

// ---------------- K1: tiled 64x64 transposes, coalesced both sides ----------------
__global__ __launch_bounds__(256) void trans_kernel(
    const float* __restrict__ wqpk, const float* __restrict__ wq, const float* __restrict__ wo,
    u16* __restrict__ wqpk_thi, u16* __restrict__ wqpk_tlo,
    u16* __restrict__ wq_t, u16* __restrict__ wo_t)
{
    int job = blockIdx.y, tile = blockIdx.x, tid = threadIdx.x;
    const float* in = (job == 0) ? wqpk : (job == 1) ? wq : wo;
    int R = (job == 2) ? 2048 : 256;
    int C = (job == 2) ? 256 : 2048;
    int CT = C >> 6;
    int tr = tile / CT, tc = tile % CT;
    __shared__ float t[64][65];
    #pragma unroll
    for (int p = 0; p < 16; p++) {
        int row = p * 4 + (tid >> 6), col = tid & 63;
        t[row][col] = in[(size_t)(tr * 64 + row) * C + tc * 64 + col];
    }
    __syncthreads();
    #pragma unroll
    for (int p = 0; p < 16; p++) {
        int row = p * 4 + (tid >> 6), col = tid & 63;
        float v = t[col][row];
        size_t o = (size_t)(tc * 64 + row) * R + tr * 64 + col;
        if (job == 0) { u16 hi = f2b(v); wqpk_thi[o] = hi; wqpk_tlo[o] = f2b(v - b2f(hi)); }
        else if (job == 1) wq_t[o] = f2b(v);
        else               wo_t[o] = f2b(v);
    }
}

// ---------------- bf16x3 MFMA GEMM (near-f32 exact): C = (Ahi+Alo)(Bhi+Blo)^T, drop lo*lo ----------------
template<int OUT_SPLIT>
__global__ __launch_bounds__(256) void gemm_x3(
    const u16* __restrict__ ahi, const u16* __restrict__ alo, int aZp, int aZh, int lda,
    const u16* __restrict__ bhi, const u16* __restrict__ blo, int bZp, int bZh, int ldb,
    void* __restrict__ c0v, void* __restrict__ c1v, int cZp, int cZh, int ldc, int K)
{
    int z = blockIdx.z, zp = z >> 3, zh = z & 7;
    size_t aoff = (size_t)zp * aZp + (size_t)zh * aZh;
    size_t boff = (size_t)zp * bZp + (size_t)zh * bZh;
    ahi += aoff; alo += aoff; bhi += boff; blo += boff;
    size_t cb = (size_t)zp * cZp + (size_t)zh * cZh;
    int m0 = blockIdx.x * 64, n0 = blockIdx.y * 64;
    int tid = threadIdx.x, lane = tid & 63, wid = tid >> 6;
    int wr = wid >> 1, wc = wid & 1, l15 = lane & 15, cg = lane >> 4;
    __shared__ __align__(16) u16 ash[64][40], asl[64][40], bsh[64][40], bsl[64][40];
    f32x4 acc[2][2];
    #pragma unroll
    for (int m = 0; m < 2; m++)
        #pragma unroll
        for (int n = 0; n < 2; n++) acc[m][n] = (f32x4){0.f, 0.f, 0.f, 0.f};
    int rs = tid >> 2, qs = tid & 3;
    for (int k0 = 0; k0 < K; k0 += 32) {
        __syncthreads();
        *(uint4*)&ash[rs][qs * 8] = *(const uint4*)(ahi + (size_t)(m0 + rs) * lda + k0 + qs * 8);
        *(uint4*)&asl[rs][qs * 8] = *(const uint4*)(alo + (size_t)(m0 + rs) * lda + k0 + qs * 8);
        *(uint4*)&bsh[rs][qs * 8] = *(const uint4*)(bhi + (size_t)(n0 + rs) * ldb + k0 + qs * 8);
        *(uint4*)&bsl[rs][qs * 8] = *(const uint4*)(blo + (size_t)(n0 + rs) * ldb + k0 + qs * 8);
        __syncthreads();
        short8 ah[2], al[2], bh[2], bl[2];
        #pragma unroll
        for (int m = 0; m < 2; m++) {
            ah[m] = *(const short8*)&ash[wr * 32 + m * 16 + l15][cg * 8];
            al[m] = *(const short8*)&asl[wr * 32 + m * 16 + l15][cg * 8];
        }
        #pragma unroll
        for (int n = 0; n < 2; n++) {
            bh[n] = *(const short8*)&bsh[wc * 32 + n * 16 + l15][cg * 8];
            bl[n] = *(const short8*)&bsl[wc * 32 + n * 16 + l15][cg * 8];
        }
        #pragma unroll
        for (int m = 0; m < 2; m++)
            #pragma unroll
            for (int n = 0; n < 2; n++) {
                acc[m][n] = __builtin_amdgcn_mfma_f32_16x16x32_bf16(al[m], bh[n], acc[m][n], 0, 0, 0);
                acc[m][n] = __builtin_amdgcn_mfma_f32_16x16x32_bf16(ah[m], bl[n], acc[m][n], 0, 0, 0);
                acc[m][n] = __builtin_amdgcn_mfma_f32_16x16x32_bf16(ah[m], bh[n], acc[m][n], 0, 0, 0);
            }
    }
    #pragma unroll
    for (int m = 0; m < 2; m++)
        #pragma unroll
        for (int n = 0; n < 2; n++)
            #pragma unroll
            for (int r = 0; r < 4; r++) {
                int row = m0 + wr * 32 + m * 16 + cg * 4 + r;
                int col = n0 + wc * 32 + n * 16 + l15;
                float v = acc[m][n][r];
                if (OUT_SPLIT) {
                    u16 hi = f2b(v);
                    ((u16*)c0v)[cb + (size_t)row * ldc + col] = hi;
                    ((u16*)c1v)[cb + (size_t)row * ldc + col] = f2b(v - b2f(hi));
                } else {
                    ((float*)c0v)[cb + (size_t)row * ldc + col] = v;
                }
            }
}

// ---------------- bf16 MFMA GEMM: C[m][n] = alpha * sum_k A[m][k] * BT[n][k], z-split-K ----------------
template<int OUT_BF16>
__global__ __launch_bounds__(256) void gemm_bt(
    const u16* __restrict__ A, int aZ, int lda,
    const u16* __restrict__ BT, int bZ, int ldb,
    void* __restrict__ Cv, size_t cZ, int ldc,
    int K, float alpha)
{
    int z = blockIdx.z;
    A  += (size_t)z * aZ;
    BT += (size_t)z * bZ;
    size_t cb = (size_t)z * cZ;
    int m0 = blockIdx.x * 64, n0 = blockIdx.y * 64;
    int tid = threadIdx.x, lane = tid & 63, wid = tid >> 6;
    int wr = wid >> 1, wc = wid & 1, l15 = lane & 15, cg = lane >> 4;
    __shared__ __align__(16) u16 as_[64][40];
    __shared__ __align__(16) u16 bs_[64][40];
    f32x4 acc[2][2];
    #pragma unroll
    for (int m = 0; m < 2; m++)
        #pragma unroll
        for (int n = 0; n < 2; n++) acc[m][n] = (f32x4){0.f, 0.f, 0.f, 0.f};
    int rs = tid >> 2, qs = tid & 3;
    for (int k0 = 0; k0 < K; k0 += 32) {
        __syncthreads();
        *(uint4*)&as_[rs][qs * 8] = *(const uint4*)(A  + (size_t)(m0 + rs) * lda + k0 + qs * 8);
        *(uint4*)&bs_[rs][qs * 8] = *(const uint4*)(BT + (size_t)(n0 + rs) * ldb + k0 + qs * 8);
        __syncthreads();
        short8 af[2], bf[2];
        #pragma unroll
        for (int m = 0; m < 2; m++) af[m] = *(const short8*)&as_[wr * 32 + m * 16 + l15][cg * 8];
        #pragma unroll
        for (int n = 0; n < 2; n++) bf[n] = *(const short8*)&bs_[wc * 32 + n * 16 + l15][cg * 8];
        #pragma unroll
        for (int m = 0; m < 2; m++)
            #pragma unroll
            for (int n = 0; n < 2; n++)
                acc[m][n] = __builtin_amdgcn_mfma_f32_16x16x32_bf16(af[m], bf[n], acc[m][n], 0, 0, 0);
    }
    #pragma unroll
    for (int m = 0; m < 2; m++)
        #pragma unroll
        for (int n = 0; n < 2; n++)
            #pragma unroll
            for (int r = 0; r < 4; r++) {
                int row = m0 + wr * 32 + m * 16 + cg * 4 + r;   // C/D: row = cg*4+reg
                int col = n0 + wc * 32 + n * 16 + l15;          //      col = lane&15
                float v = acc[m][n][r] * alpha;
                if (OUT_BF16) ((u16*)Cv)[cb + (size_t)row * ldc + col] = f2b(v);
                else          ((float*)Cv)[cb + (size_t)row * ldc + col] = v;
            }
}

// ---------------- reduce 4 split-K partials -> f32 out ----------------
__global__ __launch_bounds__(256) void reduce4_kernel(const float* __restrict__ part, float* __restrict__ out)
{
    int i = (blockIdx.x * 256 + threadIdx.x) * 4;
    float4 a = *(const float4*)(part + i);
    float4 b = *(const float4*)(part + 524288 + i);
    float4 c = *(const float4*)(part + 2 * 524288 + i);
    float4 d = *(const float4*)(part + 3 * 524288 + i);
    float4 s = {a.x + b.x + c.x + d.x, a.y + b.y + c.y + d.y,
                a.z + b.z + c.z + d.z, a.w + b.w + c.w + d.w};
    *(float4*)(out + i) = s;
}

// ---------------- K3: fused two-stage top-16 + softmax. 1 wave per (t,h). ----------------
__device__ __forceinline__ unsigned packkey(float f, int idx) {
    union { float f; unsigned u; } q; q.f = f;
    unsigned u = q.u;
    unsigned s = u ^ (unsigned)(((int)u >> 31) | 0x80000000);
    return (s & 0xFFFFFF00u) | (unsigned)(255 - idx);
}
__global__ __launch_bounds__(256) void topk_kernel(
    const float* __restrict__ sims, float* __restrict__ fw, int* __restrict__ fidx)
{
    int wid = threadIdx.x >> 6, lane = threadIdx.x & 63;
    int u = blockIdx.x * 4 + wid;     // u = t*8 + h
    int t = u >> 3, h = u & 7;
    __shared__ float lv[4][2][16];
    __shared__ int   li[4][2][16];
    __shared__ float sv[4][16];
    __shared__ int   si[4][16];
    #pragma unroll
    for (int p = 0; p < 2; p++) {
        const float* sp = sims + ((size_t)(p * 2048 + t) * 8 + h) * 256;
        float s[4]; unsigned k4[4];
        #pragma unroll
        for (int j = 0; j < 4; j++) { s[j] = sp[j * 64 + lane]; k4[j] = packkey(s[j], j * 64 + lane); }
        for (int it = 0; it < 16; ++it) {
            unsigned best = k4[0];
            #pragma unroll
            for (int j = 1; j < 4; j++) best = max(best, k4[j]);
            #pragma unroll
            for (int off = 1; off < 64; off <<= 1) {
                unsigned o = (unsigned)__shfl_xor((int)best, off, 64);
                best = max(best, o);
            }
            int idx = 255 - (int)(best & 255u);
            if (lane == (idx & 63)) { lv[wid][p][it] = s[idx >> 6]; k4[idx >> 6] = 0u; }
            if (lane == 0) li[wid][p][it] = idx;
        }
    }
    __syncthreads();
    float c[4]; unsigned kc[4];
    #pragma unroll
    for (int j = 0; j < 4; j++) {
        int cc = j * 64 + lane;
        c[j] = lv[wid][0][cc >> 4] + lv[wid][1][cc & 15];
        kc[j] = packkey(c[j], cc);
    }
    for (int it = 0; it < 16; ++it) {
        unsigned best = kc[0];
        #pragma unroll
        for (int j = 1; j < 4; j++) best = max(best, kc[j]);
        #pragma unroll
        for (int off = 1; off < 64; off <<= 1) {
            unsigned o = (unsigned)__shfl_xor((int)best, off, 64);
            best = max(best, o);
        }
        int idx = 255 - (int)(best & 255u);
        if (lane == (idx & 63)) { sv[wid][it] = c[idx >> 6]; kc[idx >> 6] = 0u; }
        if (lane == 0) si[wid][it] = idx;
    }
    __syncthreads();
    if (lane < 16) {
        float myv = sv[wid][lane];
        int cc = si[wid][lane];
        float v0 = sv[wid][0];
        float e = __expf(myv - v0);
        float ssum = e;
        #pragma unroll
        for (int off = 1; off < 16; off <<= 1) ssum += __shfl_xor(ssum, off, 16);
        int gi = li[wid][0][cc >> 4] + (li[wid][1][cc & 15] << 8) + (h << 16);
        fw[u * 16 + lane]   = e / ssum;
        fidx[u * 16 + lane] = gi;
    }
}

// ---------------- K4: weighted gather, 1 wave per (t,h), float4 lanes ----------------
__global__ __launch_bounds__(256) void gather_kernel(
    const float* __restrict__ ktab, const float* __restrict__ vtab,
    const float* __restrict__ fw, const int* __restrict__ fidx,
    u16* __restrict__ kg, u16* __restrict__ vg)
{
    int wid = threadIdx.x >> 6, lane = threadIdx.x & 63;
    int u = blockIdx.x * 4 + wid;    // t*8 + h
    int t = u >> 3, h = u & 7;
    int b = t >> 10, n = t & 1023;
    int d4 = lane * 4;
    float4 aK = {0.f, 0.f, 0.f, 0.f}, aV = {0.f, 0.f, 0.f, 0.f};
    #pragma unroll
    for (int r = 0; r < 16; r++) {
        float wgt = fw[u * 16 + r];
        size_t row = (size_t)fidx[u * 16 + r];
        float4 kv = *(const float4*)(ktab + row * 256 + d4);
        float4 vv = *(const float4*)(vtab + row * 256 + d4);
        aK.x += wgt * kv.x; aK.y += wgt * kv.y; aK.z += wgt * kv.z; aK.w += wgt * kv.w;
        aV.x += wgt * vv.x; aV.y += wgt * vv.y; aV.z += wgt * vv.z; aV.w += wgt * vv.w;
    }
    size_t o = ((size_t)(b * 8 + h) * 1024 + n) * 256 + d4;   // [bh][n][d]
    ushort4 ko = {f2b(aK.x), f2b(aK.y), f2b(aK.z), f2b(aK.w)};
    ushort4 vo = {f2b(aV.x), f2b(aV.y), f2b(aV.z), f2b(aV.w)};
    *(ushort4*)(kg + o) = ko;
    *(ushort4*)(vg + o) = vo;
}

// ---------------- K5: transpose v [bh][n][d] -> [bh][d][n] ----------------
__global__ __launch_bounds__(256) void vtrans_kernel(const u16* __restrict__ vg, u16* __restrict__ vtg)
{
    int u = blockIdx.x;                  // 16 bh * 4 dtiles * 16 ntiles
    int bh = u >> 6, dt4 = (u >> 4) & 3, nt = u & 15;
    __shared__ float tile[64][65];
    int tid = threadIdx.x;
    #pragma unroll
    for (int p = 0; p < 16; p++) {
        int flat = p * 256 + tid; int rr = flat >> 6, cc = flat & 63;
        tile[rr][cc] = b2f(vg[((size_t)bh * 1024 + nt * 64 + rr) * 256 + dt4 * 64 + cc]);
    }
    __syncthreads();
    #pragma unroll
    for (int p = 0; p < 16; p++) {
        int flat = p * 256 + tid; int od = flat >> 6, on = flat & 63;
        vtg[((size_t)bh * 256 + dt4 * 64 + od) * 1024 + nt * 64 + on] = f2b(tile[on][od]);
    }
}

// ---------------- K6: causal flash attention, 4 waves / block, Q-tile 64, kv-chunk 64 ----------------
__global__ __launch_bounds__(256) void attn_kernel(
    const u16* __restrict__ qb, const u16* __restrict__ kg, const u16* __restrict__ vtg,
    u16* __restrict__ attb)
{
    int bid = blockIdx.x;
    int bh = bid >> 4, it = bid & 15;
    int b = bh >> 3, h = bh & 7;
    int i0 = it * 64;
    int tid = threadIdx.x, lane = tid & 63, wid = tid >> 6;
    int l15 = lane & 15, cg = lane >> 4;

    __shared__ __align__(16) char ksm[64 * 512];      // K chunk [64][256] bf16, swizzled
    __shared__ __align__(16) char vts[256 * 128];     // V^T chunk [256][64] bf16, swizzled
    __shared__ __align__(16) u16  pls[4][16][72];     // per-wave P [16 rows][64 cols], pad 72

    short8 qf[8];
    const u16* qrow = qb + (size_t)(b * 1024 + i0 + wid * 16 + l15) * 2048 + h * 256 + cg * 8;
    #pragma unroll
    for (int kc = 0; kc < 8; kc++) qf[kc] = *(const short8*)(qrow + kc * 32);

    f32x4 of[16];
    #pragma unroll
    for (int dt = 0; dt < 16; dt++) of[dt] = (f32x4){0.f, 0.f, 0.f, 0.f};
    float m[4] = {-1e30f, -1e30f, -1e30f, -1e30f};
    float l[4] = {0.f, 0.f, 0.f, 0.f};

    int nch = it + 1;
    const u16* kbase = kg  + (size_t)bh * 1024 * 256;
    const u16* vbase = vtg + (size_t)bh * 256 * 1024;

    for (int jc = 0; jc < nch; ++jc) {
        int j0 = jc * 64;
        __syncthreads();
        #pragma unroll
        for (int u8 = 0; u8 < 8; ++u8) {
            int flat = u8 * 256 + tid; int r = flat >> 5, g = flat & 31;
            uint4 val = *(const uint4*)(kbase + (size_t)(j0 + r) * 256 + g * 8);
            *(uint4*)(ksm + r * 512 + ((g ^ (r & 7)) << 4)) = val;
        }
        #pragma unroll
        for (int u8 = 0; u8 < 8; ++u8) {
            int flat = u8 * 256 + tid; int d = flat >> 3, g = flat & 7;
            uint4 val = *(const uint4*)(vbase + (size_t)d * 1024 + j0 + g * 8);
            *(uint4*)(vts + d * 128 + ((g ^ (d & 7)) << 4)) = val;
        }
        __syncthreads();

        f32x4 c[4];
        #pragma unroll
        for (int ct = 0; ct < 4; ct++) c[ct] = (f32x4){0.f, 0.f, 0.f, 0.f};
        #pragma unroll
        for (int kc = 0; kc < 8; kc++) {
            int g = kc * 4 + cg;
            #pragma unroll
            for (int ct = 0; ct < 4; ct++) {
                int r = ct * 16 + l15;
                short8 bfrag = *(const short8*)(ksm + r * 512 + ((g ^ (r & 7)) << 4));
                c[ct] = __builtin_amdgcn_mfma_f32_16x16x32_bf16(qf[kc], bfrag, c[ct], 0, 0, 0);
            }
        }
        if (jc == it) {
            #pragma unroll
            for (int ct = 0; ct < 4; ct++)
                #pragma unroll
                for (int rr = 0; rr < 4; rr++)
                    if (ct * 16 + l15 > wid * 16 + cg * 4 + rr) c[ct][rr] = -1e30f;
        }
        float es[4];
        #pragma unroll
        for (int rr = 0; rr < 4; rr++) {
            float mr = fmaxf(fmaxf(c[0][rr], c[1][rr]), fmaxf(c[2][rr], c[3][rr]));
            #pragma unroll
            for (int off = 1; off < 16; off <<= 1) mr = fmaxf(mr, __shfl_xor(mr, off, 16));
            float mn = fmaxf(m[rr], mr);
            float rsum = 0.f;
            #pragma unroll
            for (int ct = 0; ct < 4; ct++) {
                float p = __expf(c[ct][rr] - mn);
                c[ct][rr] = p; rsum += p;
            }
            #pragma unroll
            for (int off = 1; off < 16; off <<= 1) rsum += __shfl_xor(rsum, off, 16);
            es[rr] = __expf(m[rr] - mn);
            l[rr] = l[rr] * es[rr] + rsum;
            m[rr] = mn;
        }
        #pragma unroll
        for (int rr = 0; rr < 4; rr++)
            #pragma unroll
            for (int ct = 0; ct < 4; ct++)
                pls[wid][cg * 4 + rr][ct * 16 + l15] = f2b(c[ct][rr]);
        #pragma unroll
        for (int dt = 0; dt < 16; dt++)
            #pragma unroll
            for (int rr = 0; rr < 4; rr++) of[dt][rr] *= es[rr];
        short8 pa0 = *(const short8*)&pls[wid][l15][cg * 8];
        short8 pa1 = *(const short8*)&pls[wid][l15][32 + cg * 8];
        #pragma unroll
        for (int dt = 0; dt < 16; ++dt) {
            int row = dt * 16 + l15;
            short8 b0 = *(const short8*)(vts + row * 128 + ((cg       ^ (row & 7)) << 4));
            short8 b1 = *(const short8*)(vts + row * 128 + (((4 + cg) ^ (row & 7)) << 4));
            of[dt] = __builtin_amdgcn_mfma_f32_16x16x32_bf16(pa0, b0, of[dt], 0, 0, 0);
            of[dt] = __builtin_amdgcn_mfma_f32_16x16x32_bf16(pa1, b1, of[dt], 0, 0, 0);
        }
    }
    float rl[4];
    #pragma unroll
    for (int rr = 0; rr < 4; rr++) rl[rr] = 1.f / l[rr];
    u16* orow = attb + (size_t)(b * 1024 + i0 + wid * 16) * 2048 + h * 256;
    #pragma unroll
    for (int dt = 0; dt < 16; dt++)
        #pragma unroll
        for (int rr = 0; rr < 4; rr++)
            orow[(size_t)(cg * 4 + rr) * 2048 + dt * 16 + l15] = f2b(of[dt][rr] * rl[rr]);
}

// ---------------- launcher ----------------
extern "C" void kernel_launch(void* const* d_in, const int* in_sizes, int n_in,
                              void* d_out, int out_size, void* d_ws, size_t ws_size,
                              hipStream_t stream) {
    (void)in_sizes; (void)n_in; (void)out_size; (void)ws_size;
    const float* x    = (const float*)d_in[0];
    const float* wqpk = (const float*)d_in[1];
    const float* pkk  = (const float*)d_in[2];
    const float* wq   = (const float*)d_in[3];
    const float* ktab = (const float*)d_in[4];
    const float* vtab = (const float*)d_in[5];
    const float* wo   = (const float*)d_in[6];
    float* out = (float*)d_out;

    char* w = (char*)d_ws;
    const size_t MB = 1u << 20;
    u16*   xhi      = (u16*)(w + 0 * MB);    // [2048][256]
    u16*   xlo      = (u16*)(w + 1 * MB);
    u16*   wqpk_thi = (u16*)(w + 2 * MB);    // [2048][256]
    u16*   wqpk_tlo = (u16*)(w + 3 * MB);
    u16*   wq_t     = (u16*)(w + 4 * MB);    // [2048][256]
    u16*   wo_t     = (u16*)(w + 5 * MB);    // [256][2048]
    u16*   pkthi    = (u16*)(w + 6 * MB);    // [2][8][256][128]
    u16*   pktlo    = (u16*)(w + 7 * MB);
    u16*   qpk_hi   = (u16*)(w + 8 * MB);    // [2048][2048] (8 MB)
    u16*   qpk_lo   = (u16*)(w + 16 * MB);
    u16*   q_b      = (u16*)(w + 24 * MB);   // [2048][2048], pre-scaled by 1/16
    float* sims     = (float*)(w + 32 * MB); // [2][2048][8][256] f32 (32 MB), dead after topk
    u16*   kg       = (u16*)(w + 32 * MB);   // [16][1024][256] (8 MB), overlays dead sims
    u16*   vg       = (u16*)(w + 40 * MB);
    u16*   vtg      = (u16*)(w + 48 * MB);   // [16][256][1024]
    u16*   attb     = (u16*)(w + 56 * MB);   // [2048][2048]
    float* fw       = (float*)(w + 64 * MB); // [16384][16]
    int*   fidx     = (int*)(w + 65 * MB);
    float* wo_part  = (float*)(w + 66 * MB); // [4][2048][256] f32 (8 MB)

    prep_elem<<<dim3(256, 2), 256, 0, stream>>>(x, pkk, xhi, xlo, pkthi, pktlo);
    trans_kernel<<<dim3(128, 3), 256, 0, stream>>>(wqpk, wq, wo, wqpk_thi, wqpk_tlo, wq_t, wo_t);
    // qpk = x @ Wq_pk  (bf16x3, split output)
    gemm_x3<1><<<dim3(32, 32, 1), 256, 0, stream>>>(xhi, xlo, 0, 0, 256,
                                                    wqpk_thi, wqpk_tlo, 0, 0, 256,
                                                    qpk_hi, qpk_lo, 0, 0, 2048, 256);
    // sims[p][t][h][key] = qpk[t,(p,h,:)] . pk_keys[p,key,h,:]  (bf16x3, f32 out), z = p*8+h
    gemm_x3<0><<<dim3(32, 4, 16), 256, 0, stream>>>(qpk_hi, qpk_lo, 1024, 128, 2048,
                                                    pkthi, pktlo, 262144, 32768, 128,
                                                    sims, nullptr, 4194304, 256, 2048, 128);
    // q = (x @ Wq) * DIM^-0.5  (bf16 MFMA)
    gemm_bt<1><<<dim3(32, 32, 1), 256, 0, stream>>>(xhi, 0, 256, wq_t, 0, 256, q_b, 0, 2048, 256, 0.0625f);
    topk_kernel<<<4096, 256, 0, stream>>>(sims, fw, fidx);
    gather_kernel<<<4096, 256, 0, stream>>>(ktab, vtab, fw, fidx, kg, vg);
    vtrans_kernel<<<1024, 256, 0, stream>>>(vg, vtg);
    attn_kernel<<<256, 256, 0, stream>>>(q_b, kg, vtg, attb);
    // out = att @ Wo  split-K=4: z covers k = z*512..z*512+511
    gemm_bt<0><<<dim3(32, 4, 4), 256, 0, stream>>>(attb, 512, 2048, wo_t, 512, 2048,
                                                   wo_part, 524288, 256, 512, 1.f);
    reduce4_kernel<<<512, 256, 0, stream>>>(wo_part, out);
}

// Round 7
// 279.885 us; speedup vs baseline: 2.2683x; 1.0101x over previous
//
#include <hip/hip_runtime.h>

typedef unsigned short u16;
typedef __attribute__((ext_vector_type(8))) short short8;   // 8 x bf16 (4 VGPRs) MFMA A/B frag
typedef __attribute__((ext_vector_type(4))) float f32x4;    // MFMA C/D frag

__device__ __forceinline__ u16 f2b(float f) {               // f32 -> bf16 RNE
    union { float f; unsigned u; } v; v.f = f;
    unsigned u = v.u;
    u += 0x7fffu + ((u >> 16) & 1u);
    return (u16)(u >> 16);
}
__device__ __forceinline__ float b2f(u16 s) {
    union { unsigned u; float f; } v; v.u = ((unsigned)s) << 16;
    return v.f;
}

// Sizes: B=2, N=1024, T=2048 tokens, H=8, D=256, DK=128, NK=256 keys, TOPK=16, NUM_KV=65536.

// ---------------- K0: elementwise bf16 hi/lo splits: x, pk_keys(permuted), Wq_pk(straight) ----------------
// ALL jobs are 524288 elements (x: [2048][256], pkt: [2][8][256][128], Wq_pk: [256][2048]).
__global__ __launch_bounds__(256) void prep_elem(
    const float* __restrict__ x, const float* __restrict__ pkk, const float* __restrict__ wqpk,
    u16* __restrict__ xhi, u16* __restrict__ xlo,
    u16* __restrict__ pkthi, u16* __restrict__ pktlo,
    u16* __restrict__ wqpkhi, u16* __restrict__ wqpklo)
{
    int job = blockIdx.y;
    for (int i = blockIdx.x * 256 + threadIdx.x; i < 524288; i += 256 * 256) {
        if (job == 0) {
            float v = x[i];
            u16 hi = f2b(v); xhi[i] = hi; xlo[i] = f2b(v - b2f(hi));
        } else if (job == 1) {
            // pkt[p][h][key][d] = pk_keys[p][key][h][d]; d innermost both sides -> coalesced
            int d = i & 127, key = (i >> 7) & 255, h = (i >> 15) & 7, p = i >> 18;
            float v = pkk[(((p << 8) + key) * 8 + h) * 128 + d];
            u16 hi = f2b(v); pkthi[i] = hi; pktlo[i] = f2b(v - b2f(hi));
        } else {
            float v = wqpk[i];                                  // [256][2048] straight split
            u16 hi = f2b(v); wqpkhi[i] = hi; wqpklo[i] = f2b(v - b2f(hi));
        }
    }
}

// ---------------- K1: tiled 64x64 transposes (Wq, Wo), coalesced both sides ----------------
__global__ __launch_bounds__(256) void trans_kernel(
    const float* __restrict__ wq, const float* __restrict__ wo,
    u16* __restrict__ wq_t, u16* __restrict__ wo_t)
{
    int job = blockIdx.y, tile = blockIdx.x, tid = threadIdx.x;
    const float* in = (job == 0) ? wq : wo;
    int R = (job == 1) ? 2048 : 256;      // rows of input
    int C = (job == 1) ? 256 : 2048;      // cols of input
    int CT = C >> 6;
    int tr = tile / CT, tc = tile % CT;
    __shared__ float t[64][65];
    #pragma unroll
    for (int p = 0; p < 16; p++) {
        int row = p * 4 + (tid >> 6), col = tid & 63;
        t[row][col] = in[(size_t)(tr * 64 + row) * C + tc * 64 + col];
    }
    __syncthreads();
    #pragma unroll
    for (int p = 0; p < 16; p++) {
        int row = p * 4 + (tid >> 6), col = tid & 63;
        float v = t[col][row];
        size_t o = (size_t)(tc * 64 + row) * R + tr * 64 + col;
        if (job == 0) wq_t[o] = f2b(v);
        else          wo_t[o] = f2b(v);
    }
}

// ---------------- K2: transpose M [256][4096] f32 -> MT [4096][256] bf16 hi/lo ----------------
__global__ __launch_bounds__(256) void mtrans_kernel(
    const float* __restrict__ Mf, u16* __restrict__ mthi, u16* __restrict__ mtlo)
{
    int tile = blockIdx.x, tid = threadIdx.x;      // 4 row-tiles x 64 col-tiles
    int tr = tile >> 6, tc = tile & 63;
    __shared__ float t[64][65];
    #pragma unroll
    for (int p = 0; p < 16; p++) {
        int row = p * 4 + (tid >> 6), col = tid & 63;
        t[row][col] = Mf[(size_t)(tr * 64 + row) * 4096 + tc * 64 + col];
    }
    __syncthreads();
    #pragma unroll
    for (int p = 0; p < 16; p++) {
        int row = p * 4 + (tid >> 6), col = tid & 63;
        float v = t[col][row];
        size_t o = (size_t)(tc * 64 + row) * 256 + tr * 64 + col;
        u16 hi = f2b(v); mthi[o] = hi; mtlo[o] = f2b(v - b2f(hi));
    }
}

// ---------------- bf16x3 MFMA GEMM (near-f32 exact): C = (Ahi+Alo)(Bhi+Blo)^T, drop lo*lo ----------------
template<int OUT_SPLIT>
__global__ __launch_bounds__(256) void gemm_x3(
    const u16* __restrict__ ahi, const u16* __restrict__ alo, int aZp, int aZh, int lda,
    const u16* __restrict__ bhi, const u16* __restrict__ blo, int bZp, int bZh, int ldb,
    void* __restrict__ c0v, void* __restrict__ c1v, int cZp, int cZh, int ldc, int K)
{
    int z = blockIdx.z, zp = z >> 3, zh = z & 7;
    size_t aoff = (size_t)zp * aZp + (size_t)zh * aZh;
    size_t boff = (size_t)zp * bZp + (size_t)zh * bZh;
    ahi += aoff; alo += aoff; bhi += boff; blo += boff;
    size_t cb = (size_t)zp * cZp + (size_t)zh * cZh;
    int m0 = blockIdx.x * 64, n0 = blockIdx.y * 64;
    int tid = threadIdx.x, lane = tid & 63, wid = tid >> 6;
    int wr = wid >> 1, wc = wid & 1, l15 = lane & 15, cg = lane >> 4;
    __shared__ __align__(16) u16 ash[64][40], asl[64][40], bsh[64][40], bsl[64][40];
    f32x4 acc[2][2];
    #pragma unroll
    for (int m = 0; m < 2; m++)
        #pragma unroll
        for (int n = 0; n < 2; n++) acc[m][n] = (f32x4){0.f, 0.f, 0.f, 0.f};
    int rs = tid >> 2, qs = tid & 3;
    for (int k0 = 0; k0 < K; k0 += 32) {
        __syncthreads();
        *(uint4*)&ash[rs][qs * 8] = *(const uint4*)(ahi + (size_t)(m0 + rs) * lda + k0 + qs * 8);
        *(uint4*)&asl[rs][qs * 8] = *(const uint4*)(alo + (size_t)(m0 + rs) * lda + k0 + qs * 8);
        *(uint4*)&bsh[rs][qs * 8] = *(const uint4*)(bhi + (size_t)(n0 + rs) * ldb + k0 + qs * 8);
        *(uint4*)&bsl[rs][qs * 8] = *(const uint4*)(blo + (size_t)(n0 + rs) * ldb + k0 + qs * 8);
        __syncthreads();
        short8 ah[2], al[2], bh[2], bl[2];
        #pragma unroll
        for (int m = 0; m < 2; m++) {
            ah[m] = *(const short8*)&ash[wr * 32 + m * 16 + l15][cg * 8];
            al[m] = *(const short8*)&asl[wr * 32 + m * 16 + l15][cg * 8];
        }
        #pragma unroll
        for (int n = 0; n < 2; n++) {
            bh[n] = *(const short8*)&bsh[wc * 32 + n * 16 + l15][cg * 8];
            bl[n] = *(const short8*)&bsl[wc * 32 + n * 16 + l15][cg * 8];
        }
        #pragma unroll
        for (int m = 0; m < 2; m++)
            #pragma unroll
            for (int n = 0; n < 2; n++) {
                acc[m][n] = __builtin_amdgcn_mfma_f32_16x16x32_bf16(al[m], bh[n], acc[m][n], 0, 0, 0);
                acc[m][n] = __builtin_amdgcn_mfma_f32_16x16x32_bf16(ah[m], bl[n], acc[m][n], 0, 0, 0);
                acc[m][n] = __builtin_amdgcn_mfma_f32_16x16x32_bf16(ah[m], bh[n], acc[m][n], 0, 0, 0);
            }
    }
    #pragma unroll
    for (int m = 0; m < 2; m++)
        #pragma unroll
        for (int n = 0; n < 2; n++)
            #pragma unroll
            for (int r = 0; r < 4; r++) {
                int row = m0 + wr * 32 + m * 16 + cg * 4 + r;
                int col = n0 + wc * 32 + n * 16 + l15;
                float v = acc[m][n][r];
                if (OUT_SPLIT) {
                    u16 hi = f2b(v);
                    ((u16*)c0v)[cb + (size_t)row * ldc + col] = hi;
                    ((u16*)c1v)[cb + (size_t)row * ldc + col] = f2b(v - b2f(hi));
                } else {
                    ((float*)c0v)[cb + (size_t)row * ldc + col] = v;
                }
            }
}

// ---------------- bf16 MFMA GEMM: C[m][n] = alpha * sum_k A[m][k] * BT[n][k], z-split-K ----------------
template<int OUT_BF16>
__global__ __launch_bounds__(256) void gemm_bt(
    const u16* __restrict__ A, int aZ, int lda,
    const u16* __restrict__ BT, int bZ, int ldb,
    void* __restrict__ Cv, size_t cZ, int ldc,
    int K, float alpha)
{
    int z = blockIdx.z;
    A  += (size_t)z * aZ;
    BT += (size_t)z * bZ;
    size_t cb = (size_t)z * cZ;
    int m0 = blockIdx.x * 64, n0 = blockIdx.y * 64;
    int tid = threadIdx.x, lane = tid & 63, wid = tid >> 6;
    int wr = wid >> 1, wc = wid & 1, l15 = lane & 15, cg = lane >> 4;
    __shared__ __align__(16) u16 as_[64][40];
    __shared__ __align__(16) u16 bs_[64][40];
    f32x4 acc[2][2];
    #pragma unroll
    for (int m = 0; m < 2; m++)
        #pragma unroll
        for (int n = 0; n < 2; n++) acc[m][n] = (f32x4){0.f, 0.f, 0.f, 0.f};
    int rs = tid >> 2, qs = tid & 3;
    for (int k0 = 0; k0 < K; k0 += 32) {
        __syncthreads();
        *(uint4*)&as_[rs][qs * 8] = *(const uint4*)(A  + (size_t)(m0 + rs) * lda + k0 + qs * 8);
        *(uint4*)&bs_[rs][qs * 8] = *(const uint4*)(BT + (size_t)(n0 + rs) * ldb + k0 + qs * 8);
        __syncthreads();
        short8 af[2], bf[2];
        #pragma unroll
        for (int m = 0; m < 2; m++) af[m] = *(const short8*)&as_[wr * 32 + m * 16 + l15][cg * 8];
        #pragma unroll
        for (int n = 0; n < 2; n++) bf[n] = *(const short8*)&bs_[wc * 32 + n * 16 + l15][cg * 8];
        #pragma unroll
        for (int m = 0; m < 2; m++)
            #pragma unroll
            for (int n = 0; n < 2; n++)
                acc[m][n] = __builtin_amdgcn_mfma_f32_16x16x32_bf16(af[m], bf[n], acc[m][n], 0, 0, 0);
    }
    #pragma unroll
    for (int m = 0; m < 2; m++)
        #pragma unroll
        for (int n = 0; n < 2; n++)
            #pragma unroll
            for (int r = 0; r < 4; r++) {
                int row = m0 + wr * 32 + m * 16 + cg * 4 + r;   // C/D: row = cg*4+reg
                int col = n0 + wc * 32 + n * 16 + l15;          //      col = lane&15
                float v = acc[m][n][r] * alpha;
                if (OUT_BF16) ((u16*)Cv)[cb + (size_t)row * ldc + col] = f2b(v);
                else          ((float*)Cv)[cb + (size_t)row * ldc + col] = v;
            }
}

// ---------------- reduce 4 split-K partials -> f32 out ----------------
__global__ __launch_bounds__(256) void reduce4_kernel(const float* __restrict__ part, float* __restrict__ out)
{
    int i = (blockIdx.x * 256 + threadIdx.x) * 4;
    float4 a = *(const float4*)(part + i);
    float4 b = *(const float4*)(part + 524288 + i);
    float4 c = *(const float4*)(part + 2 * 524288 + i);
    float4 d = *(const float4*)(part + 3 * 524288 + i);
    float4 s = {a.x + b.x + c.x + d.x, a.y + b.y + c.y + d.y,
                a.z + b.z + c.z + d.z, a.w + b.w + c.w + d.w};
    *(float4*)(out + i) = s;
}

// ---------------- K3: fused two-stage top-16 + softmax. 1 wave per (t,h). ----------------
// sims layout: [t][p*2048 + h*256 + k]
__device__ __forceinline__ unsigned packkey(float f, int idx) {
    union { float f; unsigned u; } q; q.f = f;
    unsigned u = q.u;
    unsigned s = u ^ (unsigned)(((int)u >> 31) | 0x80000000);
    return (s & 0xFFFFFF00u) | (unsigned)(255 - idx);
}
__global__ __launch_bounds__(256) void topk_kernel(
    const float* __restrict__ sims, float* __restrict__ fw, int* __restrict__ fidx)
{
    int wid = threadIdx.x >> 6, lane = threadIdx.x & 63;
    int u = blockIdx.x * 4 + wid;     // u = t*8 + h
    int t = u >> 3, h = u & 7;
    __shared__ float lv[4][2][16];
    __shared__ int   li[4][2][16];
    __shared__ float sv[4][16];
    __shared__ int   si[4][16];
    #pragma unroll
    for (int p = 0; p < 2; p++) {
        const float* sp = sims + (size_t)t * 4096 + p * 2048 + h * 256;
        float s[4]; unsigned k4[4];
        #pragma unroll
        for (int j = 0; j < 4; j++) { s[j] = sp[j * 64 + lane]; k4[j] = packkey(s[j], j * 64 + lane); }
        for (int it = 0; it < 16; ++it) {
            unsigned best = k4[0];
            #pragma unroll
            for (int j = 1; j < 4; j++) best = max(best, k4[j]);
            #pragma unroll
            for (int off = 1; off < 64; off <<= 1) {
                unsigned o = (unsigned)__shfl_xor((int)best, off, 64);
                best = max(best, o);
            }
            int idx = 255 - (int)(best & 255u);
            if (lane == (idx & 63)) { lv[wid][p][it] = s[idx >> 6]; k4[idx >> 6] = 0u; }
            if (lane == 0) li[wid][p][it] = idx;
        }
    }
    __syncthreads();
    float c[4]; unsigned kc[4];
    #pragma unroll
    for (int j = 0; j < 4; j++) {
        int cc = j * 64 + lane;
        c[j] = lv[wid][0][cc >> 4] + lv[wid][1][cc & 15];
        kc[j] = packkey(c[j], cc);
    }
    for (int it = 0; it < 16; ++it) {
        unsigned best = kc[0];
        #pragma unroll
        for (int j = 1; j < 4; j++) best = max(best, kc[j]);
        #pragma unroll
        for (int off = 1; off < 64; off <<= 1) {
            unsigned o = (unsigned)__shfl_xor((int)best, off, 64);
            best = max(best, o);
        }
        int idx = 255 - (int)(best & 255u);
        if (lane == (idx & 63)) { sv[wid][it] = c[idx >> 6]; kc[idx >> 6] = 0u; }
        if (lane == 0) si[wid][it] = idx;
    }
    __syncthreads();
    if (lane < 16) {
        float myv = sv[wid][lane];
        int cc = si[wid][lane];
        float v0 = sv[wid][0];
        float e = __expf(myv - v0);
        float ssum = e;
        #pragma unroll
        for (int off = 1; off < 16; off <<= 1) ssum += __shfl_xor(ssum, off, 16);
        int gi = li[wid][0][cc >> 4] + (li[wid][1][cc & 15] << 8) + (h << 16);
        fw[u * 16 + lane]   = e / ssum;
        fidx[u * 16 + lane] = gi;
    }
}

// ---------------- K4: weighted gather, 1 wave per (t,h), float4 lanes ----------------
__global__ __launch_bounds__(256) void gather_kernel(
    const float* __restrict__ ktab, const float* __restrict__ vtab,
    const float* __restrict__ fw, const int* __restrict__ fidx,
    u16* __restrict__ kg, u16* __restrict__ vg)
{
    int wid = threadIdx.x >> 6, lane = threadIdx.x & 63;
    int u = blockIdx.x * 4 + wid;    // t*8 + h
    int t = u >> 3, h = u & 7;
    int b = t >> 10, n = t & 1023;
    int d4 = lane * 4;
    float4 aK = {0.f, 0.f, 0.f, 0.f}, aV = {0.f, 0.f, 0.f, 0.f};
    #pragma unroll
    for (int r = 0; r < 16; r++) {
        float wgt = fw[u * 16 + r];
        size_t row = (size_t)fidx[u * 16 + r];
        float4 kv = *(const float4*)(ktab + row * 256 + d4);
        float4 vv = *(const float4*)(vtab + row * 256 + d4);
        aK.x += wgt * kv.x; aK.y += wgt * kv.y; aK.z += wgt * kv.z; aK.w += wgt * kv.w;
        aV.x += wgt * vv.x; aV.y += wgt * vv.y; aV.z += wgt * vv.z; aV.w += wgt * vv.w;
    }
    size_t o = ((size_t)(b * 8 + h) * 1024 + n) * 256 + d4;   // [bh][n][d]
    ushort4 ko = {f2b(aK.x), f2b(aK.y), f2b(aK.z), f2b(aK.w)};
    ushort4 vo = {f2b(aV.x), f2b(aV.y), f2b(aV.z), f2b(aV.w)};
    *(ushort4*)(kg + o) = ko;
    *(ushort4*)(vg + o) = vo;
}

// ---------------- K5: transpose v [bh][n][d] -> [bh][d][n] ----------------
__global__ __launch_bounds__(256) void vtrans_kernel(const u16* __restrict__ vg, u16* __restrict__ vtg)
{
    int u = blockIdx.x;                  // 16 bh * 4 dtiles * 16 ntiles
    int bh = u >> 6, dt4 = (u >> 4) & 3, nt = u & 15;
    __shared__ float tile[64][65];
    int tid = threadIdx.x;
    #pragma unroll
    for (int p = 0; p < 16; p++) {
        int flat = p * 256 + tid; int rr = flat >> 6, cc = flat & 63;
        tile[rr][cc] = b2f(vg[((size_t)bh * 1024 + nt * 64 + rr) * 256 + dt4 * 64 + cc]);
    }
    __syncthreads();
    #pragma unroll
    for (int p = 0; p < 16; p++) {
        int flat = p * 256 + tid; int od = flat >> 6, on = flat & 63;
        vtg[((size_t)bh * 256 + dt4 * 64 + od) * 1024 + nt * 64 + on] = f2b(tile[on][od]);
    }
}

// ---------------- K6: causal flash attention, 4 waves / block, Q-tile 64, kv-chunk 64 ----------------
__global__ __launch_bounds__(256) void attn_kernel(
    const u16* __restrict__ qb, const u16* __restrict__ kg, const u16* __restrict__ vtg,
    u16* __restrict__ attb)
{
    int bid = blockIdx.x;
    int bh = bid >> 4, it = bid & 15;
    int b = bh >> 3, h = bh & 7;
    int i0 = it * 64;
    int tid = threadIdx.x, lane = tid & 63, wid = tid >> 6;
    int l15 = lane & 15, cg = lane >> 4;

    __shared__ __align__(16) char ksm[64 * 512];      // K chunk [64][256] bf16, swizzled
    __shared__ __align__(16) char vts[256 * 128];     // V^T chunk [256][64] bf16, swizzled
    __shared__ __align__(16) u16  pls[4][16][72];     // per-wave P [16 rows][64 cols], pad 72

    short8 qf[8];
    const u16* qrow = qb + (size_t)(b * 1024 + i0 + wid * 16 + l15) * 2048 + h * 256 + cg * 8;
    #pragma unroll
    for (int kc = 0; kc < 8; kc++) qf[kc] = *(const short8*)(qrow + kc * 32);

    f32x4 of[16];
    #pragma unroll
    for (int dt = 0; dt < 16; dt++) of[dt] = (f32x4){0.f, 0.f, 0.f, 0.f};
    float m[4] = {-1e30f, -1e30f, -1e30f, -1e30f};
    float l[4] = {0.f, 0.f, 0.f, 0.f};

    int nch = it + 1;
    const u16* kbase = kg  + (size_t)bh * 1024 * 256;
    const u16* vbase = vtg + (size_t)bh * 256 * 1024;

    for (int jc = 0; jc < nch; ++jc) {
        int j0 = jc * 64;
        __syncthreads();
        #pragma unroll
        for (int u8 = 0; u8 < 8; ++u8) {
            int flat = u8 * 256 + tid; int r = flat >> 5, g = flat & 31;
            uint4 val = *(const uint4*)(kbase + (size_t)(j0 + r) * 256 + g * 8);
            *(uint4*)(ksm + r * 512 + ((g ^ (r & 7)) << 4)) = val;
        }
        #pragma unroll
        for (int u8 = 0; u8 < 8; ++u8) {
            int flat = u8 * 256 + tid; int d = flat >> 3, g = flat & 7;
            uint4 val = *(const uint4*)(vbase + (size_t)d * 1024 + j0 + g * 8);
            *(uint4*)(vts + d * 128 + ((g ^ (d & 7)) << 4)) = val;
        }
        __syncthreads();

        f32x4 c[4];
        #pragma unroll
        for (int ct = 0; ct < 4; ct++) c[ct] = (f32x4){0.f, 0.f, 0.f, 0.f};
        #pragma unroll
        for (int kc = 0; kc < 8; kc++) {
            int g = kc * 4 + cg;
            #pragma unroll
            for (int ct = 0; ct < 4; ct++) {
                int r = ct * 16 + l15;
                short8 bfrag = *(const short8*)(ksm + r * 512 + ((g ^ (r & 7)) << 4));
                c[ct] = __builtin_amdgcn_mfma_f32_16x16x32_bf16(qf[kc], bfrag, c[ct], 0, 0, 0);
            }
        }
        if (jc == it) {
            #pragma unroll
            for (int ct = 0; ct < 4; ct++)
                #pragma unroll
                for (int rr = 0; rr < 4; rr++)
                    if (ct * 16 + l15 > wid * 16 + cg * 4 + rr) c[ct][rr] = -1e30f;
        }
        float es[4];
        #pragma unroll
        for (int rr = 0; rr < 4; rr++) {
            float mr = fmaxf(fmaxf(c[0][rr], c[1][rr]), fmaxf(c[2][rr], c[3][rr]));
            #pragma unroll
            for (int off = 1; off < 16; off <<= 1) mr = fmaxf(mr, __shfl_xor(mr, off, 16));
            float mn = fmaxf(m[rr], mr);
            float rsum = 0.f;
            #pragma unroll
            for (int ct = 0; ct < 4; ct++) {
                float p = __expf(c[ct][rr] - mn);
                c[ct][rr] = p; rsum += p;
            }
            #pragma unroll
            for (int off = 1; off < 16; off <<= 1) rsum += __shfl_xor(rsum, off, 16);
            es[rr] = __expf(m[rr] - mn);
            l[rr] = l[rr] * es[rr] + rsum;
            m[rr] = mn;
        }
        #pragma unroll
        for (int rr = 0; rr < 4; rr++)
            #pragma unroll
            for (int ct = 0; ct < 4; ct++)
                pls[wid][cg * 4 + rr][ct * 16 + l15] = f2b(c[ct][rr]);
        #pragma unroll
        for (int dt = 0; dt < 16; dt++)
            #pragma unroll
            for (int rr = 0; rr < 4; rr++) of[dt][rr] *= es[rr];
        short8 pa0 = *(const short8*)&pls[wid][l15][cg * 8];
        short8 pa1 = *(const short8*)&pls[wid][l15][32 + cg * 8];
        #pragma unroll
        for (int dt = 0; dt < 16; ++dt) {
            int row = dt * 16 + l15;
            short8 b0 = *(const short8*)(vts + row * 128 + ((cg       ^ (row & 7)) << 4));
            short8 b1 = *(const short8*)(vts + row * 128 + (((4 + cg) ^ (row & 7)) << 4));
            of[dt] = __builtin_amdgcn_mfma_f32_16x16x32_bf16(pa0, b0, of[dt], 0, 0, 0);
            of[dt] = __builtin_amdgcn_mfma_f32_16x16x32_bf16(pa1, b1, of[dt], 0, 0, 0);
        }
    }
    float rl[4];
    #pragma unroll
    for (int rr = 0; rr < 4; rr++) rl[rr] = 1.f / l[rr];
    u16* orow = attb + (size_t)(b * 1024 + i0 + wid * 16) * 2048 + h * 256;
    #pragma unroll
    for (int dt = 0; dt < 16; dt++)
        #pragma unroll
        for (int rr = 0; rr < 4; rr++)
            orow[(size_t)(cg * 4 + rr) * 2048 + dt * 16 + l15] = f2b(of[dt][rr] * rl[rr]);
}

// ---------------- launcher ----------------
extern "C" void kernel_launch(void* const* d_in, const int* in_sizes, int n_in,
                              void* d_out, int out_size, void* d_ws, size_t ws_size,
                              hipStream_t stream) {
    (void)in_sizes; (void)n_in; (void)out_size; (void)ws_size;
    const float* x    = (const float*)d_in[0];
    const float* wqpk = (const float*)d_in[1];
    const float* pkk  = (const float*)d_in[2];
    const float* wq   = (const float*)d_in[3];
    const float* ktab = (const float*)d_in[4];
    const float* vtab = (const float*)d_in[5];
    const float* wo   = (const float*)d_in[6];
    float* out = (float*)d_out;

    char* w = (char*)d_ws;
    const size_t MB = 1u << 20;
    u16*   xhi      = (u16*)(w + 0 * MB);    // [2048][256] (1 MB each)
    u16*   xlo      = (u16*)(w + 1 * MB);
    u16*   wqpkhi   = (u16*)(w + 2 * MB);    // [256][2048] straight split (1 MB each)
    u16*   wqpklo   = (u16*)(w + 3 * MB);
    u16*   wq_t     = (u16*)(w + 4 * MB);    // [2048][256]
    u16*   wo_t     = (u16*)(w + 5 * MB);    // [256][2048]
    u16*   pkthi    = (u16*)(w + 6 * MB);    // [2][8][256][128]
    u16*   pktlo    = (u16*)(w + 7 * MB);
    float* Mf32     = (float*)(w + 8 * MB);  // [256][4096] f32 (4 MB)
    u16*   mthi     = (u16*)(w + 12 * MB);   // [4096][256] (2 MB each)
    u16*   mtlo     = (u16*)(w + 14 * MB);
    u16*   q_b      = (u16*)(w + 16 * MB);   // [2048][2048], pre-scaled by 1/16 (8 MB)
    float* sims     = (float*)(w + 24 * MB); // [2048][4096] f32 (32 MB), dead after topk
    u16*   kg       = (u16*)(w + 24 * MB);   // [16][1024][256] (8 MB), overlays dead sims
    u16*   vg       = (u16*)(w + 32 * MB);
    u16*   vtg      = (u16*)(w + 40 * MB);   // [16][256][1024]
    u16*   attb     = (u16*)(w + 48 * MB);   // [2048][2048]
    float* fw       = (float*)(w + 56 * MB); // [16384][16]
    int*   fidx     = (int*)(w + 57 * MB);
    float* wo_part  = (float*)(w + 58 * MB); // [4][2048][256] f32 (8 MB)

    prep_elem<<<dim3(256, 3), 256, 0, stream>>>(x, pkk, wqpk, xhi, xlo, pkthi, pktlo, wqpkhi, wqpklo);
    trans_kernel<<<dim3(128, 2), 256, 0, stream>>>(wq, wo, wq_t, wo_t);
    // M[c][(p,h,k)] = sum_d Wq_pk[c, p*1024+h*128+d] * pkt[p,h,k,d]  (bf16x3, f32 out), z = p*8+h
    gemm_x3<0><<<dim3(4, 4, 16), 256, 0, stream>>>(wqpkhi, wqpklo, 1024, 128, 2048,
                                                   pkthi, pktlo, 262144, 32768, 128,
                                                   Mf32, nullptr, 2048, 256, 4096, 128);
    mtrans_kernel<<<256, 256, 0, stream>>>(Mf32, mthi, mtlo);
    // sims[t][(p,h,k)] = x[t,:] . MT[(p,h,k),:]   (bf16x3, f32 out), single GEMM K=256
    gemm_x3<0><<<dim3(32, 64, 1), 256, 0, stream>>>(xhi, xlo, 0, 0, 256,
                                                    mthi, mtlo, 0, 0, 256,
                                                    sims, nullptr, 0, 0, 4096, 256);
    // q = (x @ Wq) * DIM^-0.5  (bf16 MFMA)
    gemm_bt<1><<<dim3(32, 32, 1), 256, 0, stream>>>(xhi, 0, 256, wq_t, 0, 256, q_b, 0, 2048, 256, 0.0625f);
    topk_kernel<<<4096, 256, 0, stream>>>(sims, fw, fidx);
    gather_kernel<<<4096, 256, 0, stream>>>(ktab, vtab, fw, fidx, kg, vg);
    vtrans_kernel<<<1024, 256, 0, stream>>>(vg, vtg);
    attn_kernel<<<256, 256, 0, stream>>>(q_b, kg, vtg, attb);
    // out = att @ Wo  split-K=4: z covers k = z*512..z*512+511
    gemm_bt<0><<<dim3(32, 4, 4), 256, 0, stream>>>(attb, 512, 2048, wo_t, 512, 2048,
                                                   wo_part, 524288, 256, 512, 1.f);
    reduce4_kernel<<<512, 256, 0, stream>>>(wo_part, out);
}

// Round 8
// 275.257 us; speedup vs baseline: 2.3064x; 1.0168x over previous
//
#include <hip/hip_runtime.h>

typedef unsigned short u16;
typedef __attribute__((ext_vector_type(8))) short short8;   // 8 x bf16 (4 VGPRs) MFMA A/B frag
typedef __attribute__((ext_vector_type(4))) float f32x4;    // MFMA C/D frag

__device__ __forceinline__ u16 f2b(float f) {               // f32 -> bf16 RNE
    union { float f; unsigned u; } v; v.f = f;
    unsigned u = v.u;
    u += 0x7fffu + ((u >> 16) & 1u);
    return (u16)(u >> 16);
}
__device__ __forceinline__ float b2f(u16 s) {
    union { unsigned u; float f; } v; v.u = ((unsigned)s) << 16;
    return v.f;
}
__device__ __forceinline__ void gload_lds16(const u16* g, u16* l) {
    __builtin_amdgcn_global_load_lds((const __attribute__((address_space(1))) void*)g,
                                     (__attribute__((address_space(3))) void*)l, 16, 0, 0);
}

// Sizes: B=2, N=1024, T=2048 tokens, H=8, D=256, DK=128, NK=256 keys, TOPK=16, NUM_KV=65536.

// ---------------- K0: elementwise bf16 hi/lo splits: x, pk_keys(permuted), Wq_pk(straight) ----------------
__global__ __launch_bounds__(256) void prep_elem(
    const float* __restrict__ x, const float* __restrict__ pkk, const float* __restrict__ wqpk,
    u16* __restrict__ xhi, u16* __restrict__ xlo,
    u16* __restrict__ pkthi, u16* __restrict__ pktlo,
    u16* __restrict__ wqpkhi, u16* __restrict__ wqpklo)
{
    int job = blockIdx.y;
    for (int i = blockIdx.x * 256 + threadIdx.x; i < 524288; i += 256 * 256) {
        if (job == 0) {
            float v = x[i];
            u16 hi = f2b(v); xhi[i] = hi; xlo[i] = f2b(v - b2f(hi));
        } else if (job == 1) {
            // pkt[p][h][key][d] = pk_keys[p][key][h][d]; d innermost both sides -> coalesced
            int d = i & 127, key = (i >> 7) & 255, h = (i >> 15) & 7, p = i >> 18;
            float v = pkk[(((p << 8) + key) * 8 + h) * 128 + d];
            u16 hi = f2b(v); pkthi[i] = hi; pktlo[i] = f2b(v - b2f(hi));
        } else {
            float v = wqpk[i];                                  // [256][2048] straight split
            u16 hi = f2b(v); wqpkhi[i] = hi; wqpklo[i] = f2b(v - b2f(hi));
        }
    }
}

// ---------------- K1: tiled 64x64 transposes (Wq, Wo), coalesced both sides ----------------
__global__ __launch_bounds__(256) void trans_kernel(
    const float* __restrict__ wq, const float* __restrict__ wo,
    u16* __restrict__ wq_t, u16* __restrict__ wo_t)
{
    int job = blockIdx.y, tile = blockIdx.x, tid = threadIdx.x;
    const float* in = (job == 0) ? wq : wo;
    int R = (job == 1) ? 2048 : 256;
    int C = (job == 1) ? 256 : 2048;
    int CT = C >> 6;
    int tr = tile / CT, tc = tile % CT;
    __shared__ float t[64][65];
    #pragma unroll
    for (int p = 0; p < 16; p++) {
        int row = p * 4 + (tid >> 6), col = tid & 63;
        t[row][col] = in[(size_t)(tr * 64 + row) * C + tc * 64 + col];
    }
    __syncthreads();
    #pragma unroll
    for (int p = 0; p < 16; p++) {
        int row = p * 4 + (tid >> 6), col = tid & 63;
        float v = t[col][row];
        size_t o = (size_t)(tc * 64 + row) * R + tr * 64 + col;
        if (job == 0) wq_t[o] = f2b(v);
        else          wo_t[o] = f2b(v);
    }
}

// ---------------- K2: transpose M [256][4096] f32 -> MT [4096][256] bf16 hi/lo ----------------
__global__ __launch_bounds__(256) void mtrans_kernel(
    const float* __restrict__ Mf, u16* __restrict__ mthi, u16* __restrict__ mtlo)
{
    int tile = blockIdx.x, tid = threadIdx.x;      // 4 row-tiles x 64 col-tiles
    int tr = tile >> 6, tc = tile & 63;
    __shared__ float t[64][65];
    #pragma unroll
    for (int p = 0; p < 16; p++) {
        int row = p * 4 + (tid >> 6), col = tid & 63;
        t[row][col] = Mf[(size_t)(tr * 64 + row) * 4096 + tc * 64 + col];
    }
    __syncthreads();
    #pragma unroll
    for (int p = 0; p < 16; p++) {
        int row = p * 4 + (tid >> 6), col = tid & 63;
        float v = t[col][row];
        size_t o = (size_t)(tc * 64 + row) * 256 + tr * 64 + col;
        u16 hi = f2b(v); mthi[o] = hi; mtlo[o] = f2b(v - b2f(hi));
    }
}

// ---------------- 128x128-tile MFMA GEMM with global_load_lds, NX=1 (bf16) or 3 (bf16x3) ----------------
// C[m][n] = alpha * sum_k A[m][k]*BT[n][k] (+ cross hi/lo terms when NX=3).
// LDS linear [128][32] per matrix; 16B-chunk XOR swizzle c^(r&3) applied to the GLOBAL source on
// stage and to the ds_read on consume (rule #21: both-sides-or-neither).
template<int NX, int OUT_BF16>
__global__ __launch_bounds__(256) void gemm128(
    const u16* __restrict__ ahi, const u16* __restrict__ alo, int lda,
    const u16* __restrict__ bhi, const u16* __restrict__ blo, int ldb,
    void* __restrict__ Cv, int ldc, int K, float alpha)
{
    int m0 = blockIdx.x * 128, n0 = blockIdx.y * 128;
    int tid = threadIdx.x, lane = tid & 63, wid = tid >> 6;
    int wr = wid >> 1, wc = wid & 1, l15 = lane & 15, cg = lane >> 4;
    __shared__ __align__(16) u16 sm[4][128][32];          // 32 KB: Ahi, Alo, Bhi, Blo
    f32x4 acc[4][4];
    #pragma unroll
    for (int m = 0; m < 4; m++)
        #pragma unroll
        for (int n = 0; n < 4; n++) acc[m][n] = (f32x4){0.f, 0.f, 0.f, 0.f};

    int wbase = tid & ~63;                                 // wave-uniform chunk base
    for (int k0 = 0; k0 < K; k0 += 32) {
        __syncthreads();
        #pragma unroll
        for (int i = 0; i < 2; i++) {
            int f16 = i * 256 + tid;                       // 16B-chunk idx in [0,512)
            int r = f16 >> 2, c = f16 & 3;
            int cs = (c ^ (r & 3)) * 8;                    // pre-swizzled source chunk
            u16* lbase_a = &sm[0][0][0] + (size_t)(i * 256 + wbase) * 8;
            gload_lds16(ahi + (size_t)(m0 + r) * lda + k0 + cs, lbase_a);
            u16* lbase_b = &sm[2][0][0] + (size_t)(i * 256 + wbase) * 8;
            gload_lds16(bhi + (size_t)(n0 + r) * ldb + k0 + cs, lbase_b);
            if (NX == 3) {
                u16* lbase_al = &sm[1][0][0] + (size_t)(i * 256 + wbase) * 8;
                gload_lds16(alo + (size_t)(m0 + r) * lda + k0 + cs, lbase_al);
                u16* lbase_bl = &sm[3][0][0] + (size_t)(i * 256 + wbase) * 8;
                gload_lds16(blo + (size_t)(n0 + r) * ldb + k0 + cs, lbase_bl);
            }
        }
        __syncthreads();                                   // compiler drains vmcnt before barrier

        short8 ah[4], bh[4], al[4], bl[4];
        #pragma unroll
        for (int m = 0; m < 4; m++) {
            int r = wr * 64 + m * 16 + l15;
            int cp = (cg ^ (r & 3)) * 8;                   // swizzled read chunk
            ah[m] = *(const short8*)&sm[0][r][cp];
            if (NX == 3) al[m] = *(const short8*)&sm[1][r][cp];
        }
        #pragma unroll
        for (int n = 0; n < 4; n++) {
            int r = wc * 64 + n * 16 + l15;
            int cp = (cg ^ (r & 3)) * 8;
            bh[n] = *(const short8*)&sm[2][r][cp];
            if (NX == 3) bl[n] = *(const short8*)&sm[3][r][cp];
        }
        if (NX == 3) {
            #pragma unroll
            for (int m = 0; m < 4; m++)
                #pragma unroll
                for (int n = 0; n < 4; n++)
                    acc[m][n] = __builtin_amdgcn_mfma_f32_16x16x32_bf16(al[m], bh[n], acc[m][n], 0, 0, 0);
            #pragma unroll
            for (int m = 0; m < 4; m++)
                #pragma unroll
                for (int n = 0; n < 4; n++)
                    acc[m][n] = __builtin_amdgcn_mfma_f32_16x16x32_bf16(ah[m], bl[n], acc[m][n], 0, 0, 0);
        }
        #pragma unroll
        for (int m = 0; m < 4; m++)
            #pragma unroll
            for (int n = 0; n < 4; n++)
                acc[m][n] = __builtin_amdgcn_mfma_f32_16x16x32_bf16(ah[m], bh[n], acc[m][n], 0, 0, 0);
    }
    #pragma unroll
    for (int m = 0; m < 4; m++)
        #pragma unroll
        for (int n = 0; n < 4; n++)
            #pragma unroll
            for (int r = 0; r < 4; r++) {
                int row = m0 + wr * 64 + m * 16 + cg * 4 + r;   // C/D: row = cg*4+reg
                int col = n0 + wc * 64 + n * 16 + l15;          //      col = lane&15
                float v = acc[m][n][r] * alpha;
                if (OUT_BF16) ((u16*)Cv)[(size_t)row * ldc + col] = f2b(v);
                else          ((float*)Cv)[(size_t)row * ldc + col] = v;
            }
}

// ---------------- 64-tile bf16x3 MFMA GEMM (kept for the tiny M-GEMM, z = p*8+h) ----------------
__global__ __launch_bounds__(256) void gemm_x3(
    const u16* __restrict__ ahi, const u16* __restrict__ alo, int aZp, int aZh, int lda,
    const u16* __restrict__ bhi, const u16* __restrict__ blo, int bZp, int bZh, int ldb,
    float* __restrict__ c0v, int cZp, int cZh, int ldc, int K)
{
    int z = blockIdx.z, zp = z >> 3, zh = z & 7;
    size_t aoff = (size_t)zp * aZp + (size_t)zh * aZh;
    size_t boff = (size_t)zp * bZp + (size_t)zh * bZh;
    ahi += aoff; alo += aoff; bhi += boff; blo += boff;
    size_t cb = (size_t)zp * cZp + (size_t)zh * cZh;
    int m0 = blockIdx.x * 64, n0 = blockIdx.y * 64;
    int tid = threadIdx.x, lane = tid & 63, wid = tid >> 6;
    int wr = wid >> 1, wc = wid & 1, l15 = lane & 15, cg = lane >> 4;
    __shared__ __align__(16) u16 ash[64][40], asl[64][40], bsh[64][40], bsl[64][40];
    f32x4 acc[2][2];
    #pragma unroll
    for (int m = 0; m < 2; m++)
        #pragma unroll
        for (int n = 0; n < 2; n++) acc[m][n] = (f32x4){0.f, 0.f, 0.f, 0.f};
    int rs = tid >> 2, qs = tid & 3;
    for (int k0 = 0; k0 < K; k0 += 32) {
        __syncthreads();
        *(uint4*)&ash[rs][qs * 8] = *(const uint4*)(ahi + (size_t)(m0 + rs) * lda + k0 + qs * 8);
        *(uint4*)&asl[rs][qs * 8] = *(const uint4*)(alo + (size_t)(m0 + rs) * lda + k0 + qs * 8);
        *(uint4*)&bsh[rs][qs * 8] = *(const uint4*)(bhi + (size_t)(n0 + rs) * ldb + k0 + qs * 8);
        *(uint4*)&bsl[rs][qs * 8] = *(const uint4*)(blo + (size_t)(n0 + rs) * ldb + k0 + qs * 8);
        __syncthreads();
        short8 ah[2], al[2], bh[2], bl[2];
        #pragma unroll
        for (int m = 0; m < 2; m++) {
            ah[m] = *(const short8*)&ash[wr * 32 + m * 16 + l15][cg * 8];
            al[m] = *(const short8*)&asl[wr * 32 + m * 16 + l15][cg * 8];
        }
        #pragma unroll
        for (int n = 0; n < 2; n++) {
            bh[n] = *(const short8*)&bsh[wc * 32 + n * 16 + l15][cg * 8];
            bl[n] = *(const short8*)&bsl[wc * 32 + n * 16 + l15][cg * 8];
        }
        #pragma unroll
        for (int m = 0; m < 2; m++)
            #pragma unroll
            for (int n = 0; n < 2; n++) {
                acc[m][n] = __builtin_amdgcn_mfma_f32_16x16x32_bf16(al[m], bh[n], acc[m][n], 0, 0, 0);
                acc[m][n] = __builtin_amdgcn_mfma_f32_16x16x32_bf16(ah[m], bl[n], acc[m][n], 0, 0, 0);
                acc[m][n] = __builtin_amdgcn_mfma_f32_16x16x32_bf16(ah[m], bh[n], acc[m][n], 0, 0, 0);
            }
    }
    #pragma unroll
    for (int m = 0; m < 2; m++)
        #pragma unroll
        for (int n = 0; n < 2; n++)
            #pragma unroll
            for (int r = 0; r < 4; r++) {
                int row = m0 + wr * 32 + m * 16 + cg * 4 + r;
                int col = n0 + wc * 32 + n * 16 + l15;
                c0v[cb + (size_t)row * ldc + col] = acc[m][n][r];
            }
}

// ---------------- bf16 MFMA GEMM: C[m][n] = alpha * sum_k A[m][k] * BT[n][k], z-split-K ----------------
__global__ __launch_bounds__(256) void gemm_bt(
    const u16* __restrict__ A, int aZ, int lda,
    const u16* __restrict__ BT, int bZ, int ldb,
    float* __restrict__ Cv, size_t cZ, int ldc,
    int K, float alpha)
{
    int z = blockIdx.z;
    A  += (size_t)z * aZ;
    BT += (size_t)z * bZ;
    size_t cb = (size_t)z * cZ;
    int m0 = blockIdx.x * 64, n0 = blockIdx.y * 64;
    int tid = threadIdx.x, lane = tid & 63, wid = tid >> 6;
    int wr = wid >> 1, wc = wid & 1, l15 = lane & 15, cg = lane >> 4;
    __shared__ __align__(16) u16 as_[64][40];
    __shared__ __align__(16) u16 bs_[64][40];
    f32x4 acc[2][2];
    #pragma unroll
    for (int m = 0; m < 2; m++)
        #pragma unroll
        for (int n = 0; n < 2; n++) acc[m][n] = (f32x4){0.f, 0.f, 0.f, 0.f};
    int rs = tid >> 2, qs = tid & 3;
    for (int k0 = 0; k0 < K; k0 += 32) {
        __syncthreads();
        *(uint4*)&as_[rs][qs * 8] = *(const uint4*)(A  + (size_t)(m0 + rs) * lda + k0 + qs * 8);
        *(uint4*)&bs_[rs][qs * 8] = *(const uint4*)(BT + (size_t)(n0 + rs) * ldb + k0 + qs * 8);
        __syncthreads();
        short8 af[2], bf[2];
        #pragma unroll
        for (int m = 0; m < 2; m++) af[m] = *(const short8*)&as_[wr * 32 + m * 16 + l15][cg * 8];
        #pragma unroll
        for (int n = 0; n < 2; n++) bf[n] = *(const short8*)&bs_[wc * 32 + n * 16 + l15][cg * 8];
        #pragma unroll
        for (int m = 0; m < 2; m++)
            #pragma unroll
            for (int n = 0; n < 2; n++)
                acc[m][n] = __builtin_amdgcn_mfma_f32_16x16x32_bf16(af[m], bf[n], acc[m][n], 0, 0, 0);
    }
    #pragma unroll
    for (int m = 0; m < 2; m++)
        #pragma unroll
        for (int n = 0; n < 2; n++)
            #pragma unroll
            for (int r = 0; r < 4; r++) {
                int row = m0 + wr * 32 + m * 16 + cg * 4 + r;
                int col = n0 + wc * 32 + n * 16 + l15;
                Cv[cb + (size_t)row * ldc + col] = acc[m][n][r] * alpha;
            }
}

// ---------------- reduce 4 split-K partials -> f32 out ----------------
__global__ __launch_bounds__(256) void reduce4_kernel(const float* __restrict__ part, float* __restrict__ out)
{
    int i = (blockIdx.x * 256 + threadIdx.x) * 4;
    float4 a = *(const float4*)(part + i);
    float4 b = *(const float4*)(part + 524288 + i);
    float4 c = *(const float4*)(part + 2 * 524288 + i);
    float4 d = *(const float4*)(part + 3 * 524288 + i);
    float4 s = {a.x + b.x + c.x + d.x, a.y + b.y + c.y + d.y,
                a.z + b.z + c.z + d.z, a.w + b.w + c.w + d.w};
    *(float4*)(out + i) = s;
}

// ---------------- K3: fused two-stage top-16 + softmax. 1 wave per (t,h). ----------------
// sims layout: [t][p*2048 + h*256 + k]
__device__ __forceinline__ unsigned packkey(float f, int idx) {
    union { float f; unsigned u; } q; q.f = f;
    unsigned u = q.u;
    unsigned s = u ^ (unsigned)(((int)u >> 31) | 0x80000000);
    return (s & 0xFFFFFF00u) | (unsigned)(255 - idx);
}
__global__ __launch_bounds__(256) void topk_kernel(
    const float* __restrict__ sims, float* __restrict__ fw, int* __restrict__ fidx)
{
    int wid = threadIdx.x >> 6, lane = threadIdx.x & 63;
    int u = blockIdx.x * 4 + wid;     // u = t*8 + h
    int t = u >> 3, h = u & 7;
    __shared__ float lv[4][2][16];
    __shared__ int   li[4][2][16];
    __shared__ float sv[4][16];
    __shared__ int   si[4][16];
    #pragma unroll
    for (int p = 0; p < 2; p++) {
        const float* sp = sims + (size_t)t * 4096 + p * 2048 + h * 256;
        float s[4]; unsigned k4[4];
        #pragma unroll
        for (int j = 0; j < 4; j++) { s[j] = sp[j * 64 + lane]; k4[j] = packkey(s[j], j * 64 + lane); }
        for (int it = 0; it < 16; ++it) {
            unsigned best = k4[0];
            #pragma unroll
            for (int j = 1; j < 4; j++) best = max(best, k4[j]);
            #pragma unroll
            for (int off = 1; off < 64; off <<= 1) {
                unsigned o = (unsigned)__shfl_xor((int)best, off, 64);
                best = max(best, o);
            }
            int idx = 255 - (int)(best & 255u);
            if (lane == (idx & 63)) { lv[wid][p][it] = s[idx >> 6]; k4[idx >> 6] = 0u; }
            if (lane == 0) li[wid][p][it] = idx;
        }
    }
    __syncthreads();
    float c[4]; unsigned kc[4];
    #pragma unroll
    for (int j = 0; j < 4; j++) {
        int cc = j * 64 + lane;
        c[j] = lv[wid][0][cc >> 4] + lv[wid][1][cc & 15];
        kc[j] = packkey(c[j], cc);
    }
    for (int it = 0; it < 16; ++it) {
        unsigned best = kc[0];
        #pragma unroll
        for (int j = 1; j < 4; j++) best = max(best, kc[j]);
        #pragma unroll
        for (int off = 1; off < 64; off <<= 1) {
            unsigned o = (unsigned)__shfl_xor((int)best, off, 64);
            best = max(best, o);
        }
        int idx = 255 - (int)(best & 255u);
        if (lane == (idx & 63)) { sv[wid][it] = c[idx >> 6]; kc[idx >> 6] = 0u; }
        if (lane == 0) si[wid][it] = idx;
    }
    __syncthreads();
    if (lane < 16) {
        float myv = sv[wid][lane];
        int cc = si[wid][lane];
        float v0 = sv[wid][0];
        float e = __expf(myv - v0);
        float ssum = e;
        #pragma unroll
        for (int off = 1; off < 16; off <<= 1) ssum += __shfl_xor(ssum, off, 16);
        int gi = li[wid][0][cc >> 4] + (li[wid][1][cc & 15] << 8) + (h << 16);
        fw[u * 16 + lane]   = e / ssum;
        fidx[u * 16 + lane] = gi;
    }
}

// ---------------- K4: weighted gather, 1 wave per (t,h), float4 lanes ----------------
__global__ __launch_bounds__(256) void gather_kernel(
    const float* __restrict__ ktab, const float* __restrict__ vtab,
    const float* __restrict__ fw, const int* __restrict__ fidx,
    u16* __restrict__ kg, u16* __restrict__ vg)
{
    int wid = threadIdx.x >> 6, lane = threadIdx.x & 63;
    int u = blockIdx.x * 4 + wid;    // t*8 + h
    int t = u >> 3, h = u & 7;
    int b = t >> 10, n = t & 1023;
    int d4 = lane * 4;
    float4 aK = {0.f, 0.f, 0.f, 0.f}, aV = {0.f, 0.f, 0.f, 0.f};
    #pragma unroll
    for (int r = 0; r < 16; r++) {
        float wgt = fw[u * 16 + r];
        size_t row = (size_t)fidx[u * 16 + r];
        float4 kv = *(const float4*)(ktab + row * 256 + d4);
        float4 vv = *(const float4*)(vtab + row * 256 + d4);
        aK.x += wgt * kv.x; aK.y += wgt * kv.y; aK.z += wgt * kv.z; aK.w += wgt * kv.w;
        aV.x += wgt * vv.x; aV.y += wgt * vv.y; aV.z += wgt * vv.z; aV.w += wgt * vv.w;
    }
    size_t o = ((size_t)(b * 8 + h) * 1024 + n) * 256 + d4;   // [bh][n][d]
    ushort4 ko = {f2b(aK.x), f2b(aK.y), f2b(aK.z), f2b(aK.w)};
    ushort4 vo = {f2b(aV.x), f2b(aV.y), f2b(aV.z), f2b(aV.w)};
    *(ushort4*)(kg + o) = ko;
    *(ushort4*)(vg + o) = vo;
}

// ---------------- K5: transpose v [bh][n][d] -> [bh][d][n] ----------------
__global__ __launch_bounds__(256) void vtrans_kernel(const u16* __restrict__ vg, u16* __restrict__ vtg)
{
    int u = blockIdx.x;                  // 16 bh * 4 dtiles * 16 ntiles
    int bh = u >> 6, dt4 = (u >> 4) & 3, nt = u & 15;
    __shared__ float tile[64][65];
    int tid = threadIdx.x;
    #pragma unroll
    for (int p = 0; p < 16; p++) {
        int flat = p * 256 + tid; int rr = flat >> 6, cc = flat & 63;
        tile[rr][cc] = b2f(vg[((size_t)bh * 1024 + nt * 64 + rr) * 256 + dt4 * 64 + cc]);
    }
    __syncthreads();
    #pragma unroll
    for (int p = 0; p < 16; p++) {
        int flat = p * 256 + tid; int od = flat >> 6, on = flat & 63;
        vtg[((size_t)bh * 256 + dt4 * 64 + od) * 1024 + nt * 64 + on] = f2b(tile[on][od]);
    }
}

// ---------------- K6: causal flash attention, 4 waves / block, Q-tile 64, kv-chunk 64 ----------------
__global__ __launch_bounds__(256) void attn_kernel(
    const u16* __restrict__ qb, const u16* __restrict__ kg, const u16* __restrict__ vtg,
    u16* __restrict__ attb)
{
    int bid = blockIdx.x;
    int bh = bid >> 4, it = bid & 15;
    int b = bh >> 3, h = bh & 7;
    int i0 = it * 64;
    int tid = threadIdx.x, lane = tid & 63, wid = tid >> 6;
    int l15 = lane & 15, cg = lane >> 4;

    __shared__ __align__(16) char ksm[64 * 512];      // K chunk [64][256] bf16, swizzled
    __shared__ __align__(16) char vts[256 * 128];     // V^T chunk [256][64] bf16, swizzled
    __shared__ __align__(16) u16  pls[4][16][72];     // per-wave P [16 rows][64 cols], pad 72

    short8 qf[8];
    const u16* qrow = qb + (size_t)(b * 1024 + i0 + wid * 16 + l15) * 2048 + h * 256 + cg * 8;
    #pragma unroll
    for (int kc = 0; kc < 8; kc++) qf[kc] = *(const short8*)(qrow + kc * 32);

    f32x4 of[16];
    #pragma unroll
    for (int dt = 0; dt < 16; dt++) of[dt] = (f32x4){0.f, 0.f, 0.f, 0.f};
    float m[4] = {-1e30f, -1e30f, -1e30f, -1e30f};
    float l[4] = {0.f, 0.f, 0.f, 0.f};

    int nch = it + 1;
    const u16* kbase = kg  + (size_t)bh * 1024 * 256;
    const u16* vbase = vtg + (size_t)bh * 256 * 1024;

    for (int jc = 0; jc < nch; ++jc) {
        int j0 = jc * 64;
        __syncthreads();
        #pragma unroll
        for (int u8 = 0; u8 < 8; ++u8) {
            int flat = u8 * 256 + tid; int r = flat >> 5, g = flat & 31;
            uint4 val = *(const uint4*)(kbase + (size_t)(j0 + r) * 256 + g * 8);
            *(uint4*)(ksm + r * 512 + ((g ^ (r & 7)) << 4)) = val;
        }
        #pragma unroll
        for (int u8 = 0; u8 < 8; ++u8) {
            int flat = u8 * 256 + tid; int d = flat >> 3, g = flat & 7;
            uint4 val = *(const uint4*)(vbase + (size_t)d * 1024 + j0 + g * 8);
            *(uint4*)(vts + d * 128 + ((g ^ (d & 7)) << 4)) = val;
        }
        __syncthreads();

        f32x4 c[4];
        #pragma unroll
        for (int ct = 0; ct < 4; ct++) c[ct] = (f32x4){0.f, 0.f, 0.f, 0.f};
        #pragma unroll
        for (int kc = 0; kc < 8; kc++) {
            int g = kc * 4 + cg;
            #pragma unroll
            for (int ct = 0; ct < 4; ct++) {
                int r = ct * 16 + l15;
                short8 bfrag = *(const short8*)(ksm + r * 512 + ((g ^ (r & 7)) << 4));
                c[ct] = __builtin_amdgcn_mfma_f32_16x16x32_bf16(qf[kc], bfrag, c[ct], 0, 0, 0);
            }
        }
        if (jc == it) {
            #pragma unroll
            for (int ct = 0; ct < 4; ct++)
                #pragma unroll
                for (int rr = 0; rr < 4; rr++)
                    if (ct * 16 + l15 > wid * 16 + cg * 4 + rr) c[ct][rr] = -1e30f;
        }
        float es[4];
        #pragma unroll
        for (int rr = 0; rr < 4; rr++) {
            float mr = fmaxf(fmaxf(c[0][rr], c[1][rr]), fmaxf(c[2][rr], c[3][rr]));
            #pragma unroll
            for (int off = 1; off < 16; off <<= 1) mr = fmaxf(mr, __shfl_xor(mr, off, 16));
            float mn = fmaxf(m[rr], mr);
            float rsum = 0.f;
            #pragma unroll
            for (int ct = 0; ct < 4; ct++) {
                float p = __expf(c[ct][rr] - mn);
                c[ct][rr] = p; rsum += p;
            }
            #pragma unroll
            for (int off = 1; off < 16; off <<= 1) rsum += __shfl_xor(rsum, off, 16);
            es[rr] = __expf(m[rr] - mn);
            l[rr] = l[rr] * es[rr] + rsum;
            m[rr] = mn;
        }
        #pragma unroll
        for (int rr = 0; rr < 4; rr++)
            #pragma unroll
            for (int ct = 0; ct < 4; ct++)
                pls[wid][cg * 4 + rr][ct * 16 + l15] = f2b(c[ct][rr]);
        #pragma unroll
        for (int dt = 0; dt < 16; dt++)
            #pragma unroll
            for (int rr = 0; rr < 4; rr++) of[dt][rr] *= es[rr];
        short8 pa0 = *(const short8*)&pls[wid][l15][cg * 8];
        short8 pa1 = *(const short8*)&pls[wid][l15][32 + cg * 8];
        #pragma unroll
        for (int dt = 0; dt < 16; ++dt) {
            int row = dt * 16 + l15;
            short8 b0 = *(const short8*)(vts + row * 128 + ((cg       ^ (row & 7)) << 4));
            short8 b1 = *(const short8*)(vts + row * 128 + (((4 + cg) ^ (row & 7)) << 4));
            of[dt] = __builtin_amdgcn_mfma_f32_16x16x32_bf16(pa0, b0, of[dt], 0, 0, 0);
            of[dt] = __builtin_amdgcn_mfma_f32_16x16x32_bf16(pa1, b1, of[dt], 0, 0, 0);
        }
    }
    float rl[4];
    #pragma unroll
    for (int rr = 0; rr < 4; rr++) rl[rr] = 1.f / l[rr];
    u16* orow = attb + (size_t)(b * 1024 + i0 + wid * 16) * 2048 + h * 256;
    #pragma unroll
    for (int dt = 0; dt < 16; dt++)
        #pragma unroll
        for (int rr = 0; rr < 4; rr++)
            orow[(size_t)(cg * 4 + rr) * 2048 + dt * 16 + l15] = f2b(of[dt][rr] * rl[rr]);
}

// ---------------- launcher ----------------
extern "C" void kernel_launch(void* const* d_in, const int* in_sizes, int n_in,
                              void* d_out, int out_size, void* d_ws, size_t ws_size,
                              hipStream_t stream) {
    (void)in_sizes; (void)n_in; (void)out_size; (void)ws_size;
    const float* x    = (const float*)d_in[0];
    const float* wqpk = (const float*)d_in[1];
    const float* pkk  = (const float*)d_in[2];
    const float* wq   = (const float*)d_in[3];
    const float* ktab = (const float*)d_in[4];
    const float* vtab = (const float*)d_in[5];
    const float* wo   = (const float*)d_in[6];
    float* out = (float*)d_out;

    char* w = (char*)d_ws;
    const size_t MB = 1u << 20;
    u16*   xhi      = (u16*)(w + 0 * MB);    // [2048][256] (1 MB each)
    u16*   xlo      = (u16*)(w + 1 * MB);
    u16*   wqpkhi   = (u16*)(w + 2 * MB);    // [256][2048] (1 MB each)
    u16*   wqpklo   = (u16*)(w + 3 * MB);
    u16*   wq_t     = (u16*)(w + 4 * MB);    // [2048][256]
    u16*   wo_t     = (u16*)(w + 5 * MB);    // [256][2048]
    u16*   pkthi    = (u16*)(w + 6 * MB);    // [2][8][256][128]
    u16*   pktlo    = (u16*)(w + 7 * MB);
    float* Mf32     = (float*)(w + 8 * MB);  // [256][4096] f32 (4 MB)
    u16*   mthi     = (u16*)(w + 12 * MB);   // [4096][256] (2 MB each)
    u16*   mtlo     = (u16*)(w + 14 * MB);
    u16*   q_b      = (u16*)(w + 16 * MB);   // [2048][2048], pre-scaled by 1/16 (8 MB)
    float* sims     = (float*)(w + 24 * MB); // [2048][4096] f32 (32 MB), dead after topk
    u16*   kg       = (u16*)(w + 24 * MB);   // [16][1024][256] (8 MB), overlays dead sims
    u16*   vg       = (u16*)(w + 32 * MB);
    u16*   vtg      = (u16*)(w + 40 * MB);   // [16][256][1024]
    u16*   attb     = (u16*)(w + 48 * MB);   // [2048][2048]
    float* fw       = (float*)(w + 56 * MB); // [16384][16]
    int*   fidx     = (int*)(w + 57 * MB);
    float* wo_part  = (float*)(w + 58 * MB); // [4][2048][256] f32 (8 MB)

    prep_elem<<<dim3(256, 3), 256, 0, stream>>>(x, pkk, wqpk, xhi, xlo, pkthi, pktlo, wqpkhi, wqpklo);
    trans_kernel<<<dim3(128, 2), 256, 0, stream>>>(wq, wo, wq_t, wo_t);
    // M[c][(p,h,k)] = sum_d Wq_pk[c, p*1024+h*128+d] * pkt[p,h,k,d]  (bf16x3, f32 out), z = p*8+h
    gemm_x3<<<dim3(4, 4, 16), 256, 0, stream>>>(wqpkhi, wqpklo, 1024, 128, 2048,
                                                pkthi, pktlo, 262144, 32768, 128,
                                                Mf32, 2048, 256, 4096, 128);
    mtrans_kernel<<<256, 256, 0, stream>>>(Mf32, mthi, mtlo);
    // sims[t][(p,h,k)] = x[t,:] . MT[(p,h,k),:]   (bf16x3, f32 out), 128-tile + global_load_lds
    gemm128<3, 0><<<dim3(16, 32), 256, 0, stream>>>(xhi, xlo, 256, mthi, mtlo, 256,
                                                    sims, 4096, 256, 1.f);
    // q = (x @ Wq) * DIM^-0.5  (bf16 out), 128-tile
    gemm128<1, 1><<<dim3(16, 16), 256, 0, stream>>>(xhi, xhi, 256, wq_t, wq_t, 256,
                                                    q_b, 2048, 256, 0.0625f);
    topk_kernel<<<4096, 256, 0, stream>>>(sims, fw, fidx);
    gather_kernel<<<4096, 256, 0, stream>>>(ktab, vtab, fw, fidx, kg, vg);
    vtrans_kernel<<<1024, 256, 0, stream>>>(vg, vtg);
    attn_kernel<<<256, 256, 0, stream>>>(q_b, kg, vtg, attb);
    // out = att @ Wo  split-K=4: z covers k = z*512..z*512+511
    gemm_bt<<<dim3(32, 4, 4), 256, 0, stream>>>(attb, 512, 2048, wo_t, 512, 2048,
                                                wo_part, 524288, 256, 512, 1.f);
    reduce4_kernel<<<512, 256, 0, stream>>>(wo_part, out);
}